// Round 11
// baseline (937.916 us; speedup 1.0000x reference)
//
#include <hip/hip_runtime.h>
#include <hip/hip_bf16.h>
#include <hip/hip_fp16.h>

#define NODES  16000
#define FDIM   128
#define EDGES  256000
#define NNZ_   512000

typedef __attribute__((ext_vector_type(8))) short bf16x8;
typedef __attribute__((ext_vector_type(8))) _Float16 f16x8;
typedef __attribute__((ext_vector_type(4))) float f32x4;

__device__ __forceinline__ float sigmoidf_(float z) { return 1.f / (1.f + __expf(-z)); }
__device__ __forceinline__ float bflo(unsigned u) { return __uint_as_float(u << 16); }
__device__ __forceinline__ float bfhi(unsigned u) { return __uint_as_float(u & 0xffff0000u); }
__device__ __forceinline__ unsigned pack2(float lo, float hi) {
    __hip_bfloat162 h;
    h.x = __float2bfloat16(lo);
    h.y = __float2bfloat16(hi);
    return *(unsigned*)&h;
}
__device__ __forceinline__ unsigned pk_add_f16(unsigned a, unsigned b) {
    unsigned r; asm("v_pk_add_f16 %0, %1, %2" : "=v"(r) : "v"(a), "v"(b)); return r;
}
__device__ __forceinline__ unsigned pk_relu_f16(unsigned a) {
    unsigned r; asm("v_pk_max_f16 %0, %1, %2" : "=v"(r) : "v"(a), "v"(0u)); return r;
}
__device__ __forceinline__ unsigned pkh(float lo, float hi) {
    __half2 h = __floats2half2_rn(lo, hi);
    return *(unsigned*)&h;
}
__device__ __forceinline__ float2 h2f2(unsigned u) {
    return __half22float2(*(__half2*)&u);
}

// ---------------- HyperWeight ----------------
__global__ __launch_bounds__(128) void hyperweight_k(
    const float* __restrict__ x, const float* __restrict__ ge, const int* __restrict__ batch,
    const float* __restrict__ w1, const float* __restrict__ b1,
    const float* __restrict__ w2, const float* __restrict__ b2, float* __restrict__ node_w)
{
    __shared__ float a[8][256];
    __shared__ float red[128];
    const int t = threadIdx.x;
    const int nb = blockIdx.x * 8;
    for (int u = 0; u < 8; ++u) {
        int n = nb + u;
        a[u][t]       = x[(size_t)n * FDIM + t];
        a[u][128 + t] = ge[(size_t)batch[n] * FDIM + t];
    }
    __syncthreads();
    float acc[8] = {0,0,0,0,0,0,0,0};
    for (int k = 0; k < 256; ++k) {
        float wv = w1[k * 128 + t];
        #pragma unroll
        for (int u = 0; u < 8; ++u) acc[u] += a[u][k] * wv;
    }
    const float wv2 = w2[t];
    for (int u = 0; u < 8; ++u) {
        float h = fmaxf(acc[u] + b1[t], 0.f);
        red[t] = h * wv2;
        __syncthreads();
        for (int s2 = 64; s2 > 0; s2 >>= 1) {
            if (t < s2) red[t] += red[t + s2];
            __syncthreads();
        }
        if (t == 0) node_w[nb + u] = sigmoidf_(red[0] + b2[0]);
        __syncthreads();
    }
}

// ---------------- incidence pass ----------------
__global__ void incidence_pass(const int* __restrict__ he, const float* __restrict__ node_w,
                               float* __restrict__ D, int* __restrict__ Bcnt, int* __restrict__ rowCnt)
{
    int i = blockIdx.x * 256 + threadIdx.x;
    if (i >= NNZ_) return;
    int hr = he[i];
    int hc = he[NNZ_ + i];
    int hc2 = he[NNZ_ + hc];              // repo quirk: w = node_w[hcol[hcol[i]]]
    atomicAdd(&D[hr], node_w[hc2]);
    atomicAdd(&Bcnt[hc], 1);
    atomicAdd(&rowCnt[hr], 1);
}

// fused: Dinv (edges) + Binv (nodes)
__global__ void inv_k(float* __restrict__ D, const int* __restrict__ Bcnt, float* __restrict__ Binv) {
    int i = blockIdx.x * 256 + threadIdx.x;
    if (i < EDGES) {
        float d = D[i];
        D[i] = (d != 0.f) ? 1.f / d : 0.f;
    }
    if (i < NODES) {
        int c = Bcnt[i];
        Binv[i] = c ? 1.f / (float)c : 0.f;
    }
}

// ---------------- exclusive scan (3-kernel) ----------------
__global__ __launch_bounds__(1024) void reduce_chunks(const int* __restrict__ in, int* __restrict__ part, int n) {
    __shared__ int s[1024];
    int t = threadIdx.x, g = blockIdx.x * 1024 + t;
    s[t] = (g < n) ? in[g] : 0;
    __syncthreads();
    for (int d = 512; d > 0; d >>= 1) {
        if (t < d) s[t] += s[t + d];
        __syncthreads();
    }
    if (t == 0) part[blockIdx.x] = s[0];
}
__global__ __launch_bounds__(1024) void scan_sums(int* __restrict__ part, int nc) {
    __shared__ int s[1024];
    int t = threadIdx.x;
    int v = (t < nc) ? part[t] : 0;
    s[t] = v;
    __syncthreads();
    for (int d = 1; d < 1024; d <<= 1) {
        int tv = (t >= d) ? s[t - d] : 0;
        __syncthreads();
        s[t] += tv;
        __syncthreads();
    }
    if (t < nc) part[t] = s[t] - v;     // exclusive
}
__global__ __launch_bounds__(1024) void scan_chunks(const int* __restrict__ in, const int* __restrict__ part,
                                                    int* __restrict__ out, int n) {
    __shared__ int s[1024];
    int t = threadIdx.x, g = blockIdx.x * 1024 + t;
    int v = (g < n) ? in[g] : 0;
    s[t] = v;
    __syncthreads();
    for (int d = 1; d < 1024; d <<= 1) {
        int tv = (t >= d) ? s[t - d] : 0;
        __syncthreads();
        s[t] += tv;
        __syncthreads();
    }
    int excl = s[t] - v + part[blockIdx.x];
    if (g < n) out[g] = excl;
    if (g == n - 1) out[n] = excl + v;
}

// ---------------- scatter into CSR lists ----------------
__global__ void scatter_pass(const int* __restrict__ he, const int* __restrict__ colOff, const int* __restrict__ rowOff,
                             int* __restrict__ colCur, int* __restrict__ rowCur,
                             int* __restrict__ colList, int* __restrict__ rowList)
{
    int i = blockIdx.x * 256 + threadIdx.x;
    if (i >= NNZ_) return;
    int hr = he[i];
    int hc = he[NNZ_ + i];
    int p = colOff[hc] + atomicAdd(&colCur[hc], 1);
    colList[p] = hr;
    int q = rowOff[hr] + atomicAdd(&rowCur[hr], 1);
    rowList[q] = hc;
}

// ---------------- conversion helpers ----------------
__global__ void conv_x(const float* __restrict__ in, __hip_bfloat16* __restrict__ ob,
                       _Float16* __restrict__ oh, int n) {
    int i = blockIdx.x * 256 + threadIdx.x;
    if (i < n) { float v = in[i]; ob[i] = __float2bfloat16(v); oh[i] = (_Float16)v; }
}
__global__ void conv_f16(const float* __restrict__ in, _Float16* __restrict__ out, int n) {
    int i = blockIdx.x * 256 + threadIdx.x;
    if (i < n) out[i] = (_Float16)in[i];
}
// in [K][N] fp32 -> out [N][K] fp16
__global__ void transpose_f16(const float* __restrict__ in, _Float16* __restrict__ out, int K, int N) {
    int i = blockIdx.x * 256 + threadIdx.x;
    if (i >= K * N) return;
    int n = i / K, k = i - n * K;
    out[i] = (_Float16)in[k * N + n];
}

// ---------------- agg1[n,256] = sum over edges r in col(n) of [xb[ei0[r]] | xb[ei1[r]]] ----
__global__ __launch_bounds__(128) void col_gather_x(
    const __hip_bfloat16* __restrict__ xb, const int* __restrict__ ei,
    const int* __restrict__ colOff, const int* __restrict__ colList, float* __restrict__ agg)
{
    int n = blockIdx.x;
    int t = threadIdx.x;
    int base = (t < 64) ? 0 : EDGES;
    int f = t & 63;
    const unsigned* x32 = (const unsigned*)xb;
    int s = colOff[n], e = colOff[n + 1];
    float vx = 0.f, vy = 0.f;
    int j = s;
    for (; j + 3 < e; j += 4) {
        int r0 = colList[j], r1 = colList[j + 1], r2 = colList[j + 2], r3 = colList[j + 3];
        unsigned q0 = x32[(size_t)ei[base + r0] * 64 + f];
        unsigned q1 = x32[(size_t)ei[base + r1] * 64 + f];
        unsigned q2 = x32[(size_t)ei[base + r2] * 64 + f];
        unsigned q3 = x32[(size_t)ei[base + r3] * 64 + f];
        vx += bflo(q0) + bflo(q1) + bflo(q2) + bflo(q3);
        vy += bfhi(q0) + bfhi(q1) + bfhi(q2) + bfhi(q3);
    }
    for (; j < e; ++j) {
        unsigned q0 = x32[(size_t)ei[base + colList[j]] * 64 + f];
        vx += bflo(q0); vy += bfhi(q0);
    }
    int ob = (t < 64) ? 0 : 128;
    float2 o = make_float2(vx, vy);
    *(float2*)(agg + (size_t)n * 256 + ob + 2 * f) = o;
}

// ---------------- er[r,256] (bf16) = sigmoid(Dinv[r]*rowsum(oe1) + c1_b) ----------------
__global__ __launch_bounds__(128) void er_k(
    const __hip_bfloat16* __restrict__ oe1, const int* __restrict__ rowOff,
    const int* __restrict__ rowList, const float* __restrict__ Dinv,
    const float* __restrict__ c1b, __hip_bfloat16* __restrict__ er)
{
    int r = blockIdx.x;
    int t = threadIdx.x;
    int s = rowOff[r], e = rowOff[r + 1];
    const unsigned* o32 = (const unsigned*)oe1;
    float vx = 0.f, vy = 0.f;
    int j = s;
    for (; j + 1 < e; j += 2) {
        unsigned q0 = o32[(size_t)rowList[j] * 128 + t];
        unsigned q1 = o32[(size_t)rowList[j + 1] * 128 + t];
        vx += bflo(q0) + bflo(q1);
        vy += bfhi(q0) + bfhi(q1);
    }
    if (j < e) {
        unsigned q0 = o32[(size_t)rowList[j] * 128 + t];
        vx += bflo(q0); vy += bfhi(q0);
    }
    float dv = Dinv[r];
    *(unsigned*)(er + (size_t)r * 256 + 2 * t) =
        pack2(sigmoidf_(dv * vx + c1b[2 * t]), sigmoidf_(dv * vy + c1b[2 * t + 1]));
}

// ---------------- agg2[n,256] = sum over r in col(n) of er[r] ----------------
__global__ __launch_bounds__(128) void col_agg_er(
    const __hip_bfloat16* __restrict__ er, const int* __restrict__ colOff,
    const int* __restrict__ colList, float* __restrict__ agg)
{
    int n = blockIdx.x;
    int t = threadIdx.x;
    const unsigned* e32 = (const unsigned*)er;
    int s = colOff[n], e = colOff[n + 1];
    float vx = 0.f, vy = 0.f;
    int j = s;
    for (; j + 3 < e; j += 4) {
        unsigned q0 = e32[(size_t)colList[j]     * 128 + t];
        unsigned q1 = e32[(size_t)colList[j + 1] * 128 + t];
        unsigned q2 = e32[(size_t)colList[j + 2] * 128 + t];
        unsigned q3 = e32[(size_t)colList[j + 3] * 128 + t];
        vx += bflo(q0) + bflo(q1) + bflo(q2) + bflo(q3);
        vy += bfhi(q0) + bfhi(q1) + bfhi(q2) + bfhi(q3);
    }
    for (; j < e; ++j) {
        unsigned q0 = e32[(size_t)colList[j] * 128 + t];
        vx += bflo(q0); vy += bfhi(q0);
    }
    float2 o = make_float2(vx, vy);
    *(float2*)(agg + (size_t)n * 256 + 2 * t) = o;
}

// ---------------- node-rows fp32 GEMM: C = rowscale ⊙ (A @ B) ----------------
template<int K, int NN, bool OB16>
__global__ __launch_bounds__(256) void gemm_node(
    const float* __restrict__ A, const float* __restrict__ B,
    const float* __restrict__ rowscale, void* __restrict__ C)
{
    __shared__ float As[16][68];
    __shared__ float Bs[16][68];
    const int tid = threadIdx.x;
    const int m0 = blockIdx.x * 64, n0 = blockIdx.y * 64;
    const int la_k = tid & 15, la_m = tid >> 4;
    const int lb_n = tid & 63, lb_k = tid >> 6;
    const int tn = tid & 15, tm = tid >> 4;
    float acc[4][4] = {};
    for (int k0 = 0; k0 < K; k0 += 16) {
        #pragma unroll
        for (int r = 0; r < 4; ++r)
            As[la_k][la_m + 16 * r] = A[(size_t)(m0 + la_m + 16 * r) * K + k0 + la_k];
        #pragma unroll
        for (int r = 0; r < 4; ++r)
            Bs[lb_k + 4 * r][lb_n] = B[(size_t)(k0 + lb_k + 4 * r) * NN + n0 + lb_n];
        __syncthreads();
        #pragma unroll
        for (int kk = 0; kk < 16; ++kk) {
            float4 av = *(const float4*)&As[kk][tm * 4];
            float4 bv = *(const float4*)&Bs[kk][tn * 4];
            float am[4] = {av.x, av.y, av.z, av.w};
            float bn[4] = {bv.x, bv.y, bv.z, bv.w};
            #pragma unroll
            for (int i = 0; i < 4; ++i)
                #pragma unroll
                for (int j = 0; j < 4; ++j)
                    acc[i][j] += am[i] * bn[j];
        }
        __syncthreads();
    }
    #pragma unroll
    for (int i = 0; i < 4; ++i) {
        int m = m0 + tm * 4 + i;
        float rs = rowscale[m];
        if constexpr (OB16) {
            __hip_bfloat16* Cp = (__hip_bfloat16*)C + (size_t)m * NN + n0 + tn * 4;
            #pragma unroll
            for (int j = 0; j < 4; ++j) Cp[j] = __float2bfloat16(rs * acc[i][j]);
        } else {
            float4 o = make_float4(rs * acc[i][0], rs * acc[i][1], rs * acc[i][2], rs * acc[i][3]);
            *(float4*)((float*)C + (size_t)m * NN + n0 + tn * 4) = o;
        }
    }
}

// ---------------- fp16 MFMA GEMM, 64x128 tile: dst[M][512] (optionally + gc[batch]+b1) ------
template<int LDB, bool XAG>
__global__ __launch_bounds__(256) void xw_f16(
    const _Float16* __restrict__ A, const _Float16* __restrict__ Bt, _Float16* __restrict__ dst,
    const _Float16* __restrict__ gct, const int* __restrict__ batch, const float* __restrict__ bias)
{
    __shared__ __align__(16) _Float16 As[64][40];
    __shared__ __align__(16) _Float16 Bs[128][40];
    const int tid = threadIdx.x;
    const int m0 = blockIdx.x * 64, n0 = blockIdx.y * 128;
    const int wave = tid >> 6, lane = tid & 63;
    const int wr = wave >> 1, wc = wave & 1;
    const int srow = tid >> 2, kseg = (tid & 3) * 8;
    const int nr = tid >> 1, kb = (tid & 1) * 16;
    const int fr = lane & 15, krow = (lane >> 4) * 8, rq = lane >> 4;

    f32x4 acc[2][4] = {};
    for (int k0 = 0; k0 < 128; k0 += 32) {
        *(uint4*)&As[srow][kseg] = *(const uint4*)(A + (size_t)(m0 + srow) * 128 + k0 + kseg);
        *(uint4*)&Bs[nr][kb]     = *(const uint4*)(Bt + (size_t)(n0 + nr) * LDB + k0 + kb);
        *(uint4*)&Bs[nr][kb + 8] = *(const uint4*)(Bt + (size_t)(n0 + nr) * LDB + k0 + kb + 8);
        __syncthreads();
        f16x8 af[2], bf[4];
        #pragma unroll
        for (int i = 0; i < 2; ++i) af[i] = *(const f16x8*)&As[wr * 32 + i * 16 + fr][krow];
        #pragma unroll
        for (int j = 0; j < 4; ++j) bf[j] = *(const f16x8*)&Bs[wc * 64 + j * 16 + fr][krow];
        #pragma unroll
        for (int i = 0; i < 2; ++i)
            #pragma unroll
            for (int j = 0; j < 4; ++j)
                acc[i][j] = __builtin_amdgcn_mfma_f32_16x16x32_f16(af[i], bf[j], acc[i][j], 0, 0, 0);
        __syncthreads();
    }
    #pragma unroll
    for (int i = 0; i < 2; ++i)
        #pragma unroll
        for (int j = 0; j < 4; ++j) {
            int col = n0 + wc * 64 + j * 16 + fr;
            #pragma unroll
            for (int r = 0; r < 4; ++r) {
                int row = m0 + wr * 32 + i * 16 + rq * 4 + r;
                float v = acc[i][j][r];
                if constexpr (XAG)
                    v += (float)gct[(size_t)batch[row] * 512 + col] + bias[col];
                dst[(size_t)row * 512 + col] = (_Float16)v;
            }
        }
}

// ---------------- fused generator-L2 + classifier: register-direct fragments ----------------
// Phase 1 (no LDS, no barriers): xl = relu(relu(xag[col]+xb2[row]) @ gw2t + g_b2) -> xlt (padded LDS)
// Phase 2: out = sigmoid( relu([a0*xl + a1*sij_inline | geh[gi]] @ clw1t + cl_b1)·w2 + cl_b2 )
__global__ __launch_bounds__(256) void gencls_mfma(
    const _Float16* __restrict__ xag, const _Float16* __restrict__ xb2,
    const _Float16* __restrict__ gw2t, const float* __restrict__ gb2,
    const _Float16* __restrict__ geh, const float* __restrict__ attn,
    const _Float16* __restrict__ clw1t, const float* __restrict__ clb1,
    const float* __restrict__ w2, const float* __restrict__ b2, const float* __restrict__ c2b,
    const __hip_bfloat16* __restrict__ oe2,
    const int* __restrict__ ei, const int* __restrict__ batch,
    const int* __restrict__ rowOff, const int* __restrict__ rowList, const float* __restrict__ Dinv,
    float* __restrict__ out)
{
    __shared__ __align__(16) _Float16 xlt[64][136];   // padded: row stride 272 B (4-bank rotation)
    const int tid = threadIdx.x;
    const int m0 = blockIdx.x * 64;
    const int wave = tid >> 6, lane = tid & 63;
    const int wr = wave >> 1, wc = wave & 1;
    const int fr = lane & 15, rq = lane >> 4, krow = rq * 8;

    // ---- phase 1: per-lane fragment-direct loads ----
    const int e0 = m0 + wr * 32 + fr;
    const int e1 = e0 + 16;
    const _Float16* pa0 = xag + (size_t)ei[e0] * 512;
    const _Float16* pb0 = xb2 + (size_t)ei[EDGES + e0] * 512;
    const _Float16* pa1 = xag + (size_t)ei[e1] * 512;
    const _Float16* pb1 = xb2 + (size_t)ei[EDGES + e1] * 512;
    const _Float16* pw1 = gw2t + (size_t)(wc * 64 + fr) * 512;

    f32x4 acc[2][4] = {};
    for (int k0 = 0; k0 < 512; k0 += 32) {
        int kg = k0 + krow;
        uint4 ua0 = *(const uint4*)(pa0 + kg);
        uint4 ub0 = *(const uint4*)(pb0 + kg);
        uint4 ua1 = *(const uint4*)(pa1 + kg);
        uint4 ub1 = *(const uint4*)(pb1 + kg);
        uint4 f0, f1;
        f0.x = pk_relu_f16(pk_add_f16(ua0.x, ub0.x));
        f0.y = pk_relu_f16(pk_add_f16(ua0.y, ub0.y));
        f0.z = pk_relu_f16(pk_add_f16(ua0.z, ub0.z));
        f0.w = pk_relu_f16(pk_add_f16(ua0.w, ub0.w));
        f1.x = pk_relu_f16(pk_add_f16(ua1.x, ub1.x));
        f1.y = pk_relu_f16(pk_add_f16(ua1.y, ub1.y));
        f1.z = pk_relu_f16(pk_add_f16(ua1.z, ub1.z));
        f1.w = pk_relu_f16(pk_add_f16(ua1.w, ub1.w));
        f16x8 af0 = *(f16x8*)&f0;
        f16x8 af1 = *(f16x8*)&f1;
        #pragma unroll
        for (int j = 0; j < 4; ++j) {
            f16x8 bf = *(const f16x8*)(pw1 + (size_t)j * 16 * 512 + kg);
            acc[0][j] = __builtin_amdgcn_mfma_f32_16x16x32_f16(af0, bf, acc[0][j], 0, 0, 0);
            acc[1][j] = __builtin_amdgcn_mfma_f32_16x16x32_f16(af1, bf, acc[1][j], 0, 0, 0);
        }
    }
    // xl tile -> padded LDS (bias + relu), C-layout scatter
    #pragma unroll
    for (int i = 0; i < 2; ++i)
        #pragma unroll
        for (int j = 0; j < 4; ++j) {
            int col = wc * 64 + j * 16 + fr;
            float bc = gb2[col];
            #pragma unroll
            for (int r = 0; r < 4; ++r) {
                int row = wr * 32 + i * 16 + rq * 4 + r;
                xlt[row][col] = (_Float16)fmaxf(acc[i][j][r] + bc, 0.f);
            }
        }
    __syncthreads();

    // ---- phase 2: classifier GEMM (K=256) + fused dot ----
    const float a0 = attn[0], a1 = attn[1];
    const int row_l = wave * 16 + fr;
    const int e2 = m0 + row_l;
    const int gi = batch[ei[e2]];
    const int rs = rowOff[e2], re = rowOff[e2 + 1];
    const float dv = Dinv[e2];
    const _Float16* pw2 = clw1t + (size_t)fr * 256;

    f32x4 acc2[8] = {};
    for (int it = 0; it < 8; ++it) {
        int kg = it * 32 + krow;
        f16x8 af;
        if (it < 4) {
            uint4 u = *(const uint4*)&xlt[row_l][kg];
            float s0 = 0.f, s1 = 0.f, s2 = 0.f, s3 = 0.f, s4 = 0.f, s5 = 0.f, s6 = 0.f, s7 = 0.f;
            for (int q = rs; q < re; ++q) {
                uint4 o = *(const uint4*)(oe2 + (size_t)rowList[q] * 128 + kg);
                s0 += bflo(o.x); s1 += bfhi(o.x); s2 += bflo(o.y); s3 += bfhi(o.y);
                s4 += bflo(o.z); s5 += bfhi(o.z); s6 += bflo(o.w); s7 += bfhi(o.w);
            }
            float4 c0 = *(const float4*)(c2b + kg);
            float4 c1 = *(const float4*)(c2b + kg + 4);
            float2 g0 = h2f2(u.x), g1 = h2f2(u.y), g2 = h2f2(u.z), g3 = h2f2(u.w);
            uint4 av;
            av.x = pkh(a0 * g0.x + a1 * sigmoidf_(dv * s0 + c0.x),
                       a0 * g0.y + a1 * sigmoidf_(dv * s1 + c0.y));
            av.y = pkh(a0 * g1.x + a1 * sigmoidf_(dv * s2 + c0.z),
                       a0 * g1.y + a1 * sigmoidf_(dv * s3 + c0.w));
            av.z = pkh(a0 * g2.x + a1 * sigmoidf_(dv * s4 + c1.x),
                       a0 * g2.y + a1 * sigmoidf_(dv * s5 + c1.y));
            av.w = pkh(a0 * g3.x + a1 * sigmoidf_(dv * s6 + c1.z),
                       a0 * g3.y + a1 * sigmoidf_(dv * s7 + c1.w));
            af = *(f16x8*)&av;
        } else {
            af = *(const f16x8*)(geh + (size_t)gi * 128 + kg - 128);
        }
        #pragma unroll
        for (int j = 0; j < 8; ++j) {
            f16x8 bf = *(const f16x8*)(pw2 + (size_t)j * 16 * 256 + kg);
            acc2[j] = __builtin_amdgcn_mfma_f32_16x16x32_f16(af, bf, acc2[j], 0, 0, 0);
        }
    }
    // epilogue: relu(+clb1), dot w2, 16-lane reduce, sigmoid
    float rsum[4] = {0.f, 0.f, 0.f, 0.f};
    #pragma unroll
    for (int j = 0; j < 8; ++j) {
        int colg = j * 16 + fr;
        float bc = clb1[colg];
        float wv = w2[colg];
        #pragma unroll
        for (int r = 0; r < 4; ++r)
            rsum[r] += fmaxf(acc2[j][r] + bc, 0.f) * wv;
    }
    #pragma unroll
    for (int m = 1; m < 16; m <<= 1) {
        #pragma unroll
        for (int r = 0; r < 4; ++r) rsum[r] += __shfl_xor(rsum[r], m, 64);
    }
    if (fr == 0) {
        float bb = b2[0];
        #pragma unroll
        for (int r = 0; r < 4; ++r)
            out[m0 + wave * 16 + rq * 4 + r] = sigmoidf_(rsum[r] + bb);
    }
}

// =======================================================================================
extern "C" void kernel_launch(void* const* d_in, const int* in_sizes, int n_in,
                              void* d_out, int out_size, void* d_ws, size_t ws_size,
                              hipStream_t stream)
{
    const float* x     = (const float*)d_in[0];
    const float* ge    = (const float*)d_in[1];
    const int*   ei    = (const int*)d_in[2];
    const int*   batch = (const int*)d_in[4];
    const int*   he    = (const int*)d_in[5];
    const float* hw_w1 = (const float*)d_in[6];
    const float* hw_b1 = (const float*)d_in[7];
    const float* hw_w2 = (const float*)d_in[8];
    const float* hw_b2 = (const float*)d_in[9];
    const float* c1_w  = (const float*)d_in[10];
    const float* c1_b  = (const float*)d_in[11];
    const float* c2_w  = (const float*)d_in[12];
    const float* c2_b  = (const float*)d_in[13];
    const float* g_w1  = (const float*)d_in[14];
    const float* g_b1  = (const float*)d_in[15];
    const float* g_w2  = (const float*)d_in[16];
    const float* g_b2  = (const float*)d_in[17];
    const float* cl_w1 = (const float*)d_in[18];
    const float* cl_b1 = (const float*)d_in[19];
    const float* cl_w2 = (const float*)d_in[20];
    const float* cl_b2 = (const float*)d_in[21];
    const float* attn  = (const float*)d_in[22];
    float* out = (float*)d_out;

    char* ws = (char*)d_ws;
    size_t off = 0;
    auto alloc = [&](size_t nb) -> void* {
        off = (off + 255) & ~(size_t)255;
        void* p = ws + off;
        off += nb;
        return p;
    };
    // ---- zero region (one memset): D, Bcnt, rowCnt, colCur, rowCur ----
    float* D      = (float*)alloc((size_t)EDGES * 4);   // becomes Dinv in place
    int*   Bcnt   = (int*)  alloc((size_t)NODES * 4);
    int*   rowCnt = (int*)  alloc((size_t)EDGES * 4);
    int*   colCur = (int*)  alloc((size_t)NODES * 4);
    int*   rowCur = (int*)  alloc((size_t)EDGES * 4);
    size_t zero_end = off;
    // ---- other small arrays ----
    float* node_w = (float*)alloc((size_t)NODES * 4);
    float* Binv   = (float*)alloc((size_t)NODES * 4);
    int*   colOff = (int*)  alloc((size_t)(NODES + 1) * 4);
    int*   rowOff = (int*)  alloc((size_t)(EDGES + 1) * 4);
    int*   colList= (int*)  alloc((size_t)NNZ_ * 4);
    int*   rowList= (int*)  alloc((size_t)NNZ_ * 4);
    int*   partA  = (int*)  alloc(1024 * 4);
    int*   partB  = (int*)  alloc(1024 * 4);
    // dtype tables (~10 MB)
    __hip_bfloat16* xb    = (__hip_bfloat16*)alloc((size_t)NODES * FDIM * 2);
    _Float16* xh    = (_Float16*)alloc((size_t)NODES * FDIM * 2);
    _Float16* geh   = (_Float16*)alloc((size_t)512 * FDIM * 2);
    _Float16* gw1t  = (_Float16*)alloc((size_t)512 * 384 * 2);
    _Float16* gw2t  = (_Float16*)alloc((size_t)128 * 512 * 2);
    _Float16* clw1t = (_Float16*)alloc((size_t)128 * 256 * 2);
    // generator split tables (~33.5 MB)
    _Float16* xag   = (_Float16*)alloc((size_t)NODES * 512 * 2);
    _Float16* xb2   = (_Float16*)alloc((size_t)NODES * 512 * 2);
    _Float16* gc    = (_Float16*)alloc((size_t)512 * 512 * 2);
    // big buffers
    float* agg  = (float*)alloc((size_t)NODES * 256 * 4);                    // 16.4 MB
    __hip_bfloat16* oe1b = (__hip_bfloat16*)alloc((size_t)NODES * 256 * 2);  // 8.2 MB
    __hip_bfloat16* oe2  = (__hip_bfloat16*)alloc((size_t)NODES * 128 * 2);  // 4.1 MB
    __hip_bfloat16* er   = (__hip_bfloat16*)alloc((size_t)EDGES * 256 * 2);  // 131 MB

    hipMemsetAsync(D, 0, zero_end, stream);   // zeroes D..rowCur (incl. align pads)

    hyperweight_k<<<NODES / 8, 128, 0, stream>>>(x, ge, batch, hw_w1, hw_b1, hw_w2, hw_b2, node_w);
    incidence_pass<<<NNZ_ / 256, 256, 0, stream>>>(he, node_w, D, Bcnt, rowCnt);
    inv_k<<<EDGES / 256, 256, 0, stream>>>(D, Bcnt, Binv);

    const int ncN = (NODES + 1023) / 1024;
    const int ncE = (EDGES + 1023) / 1024;
    reduce_chunks<<<ncN, 1024, 0, stream>>>(Bcnt, partA, NODES);
    scan_sums<<<1, 1024, 0, stream>>>(partA, ncN);
    scan_chunks<<<ncN, 1024, 0, stream>>>(Bcnt, partA, colOff, NODES);
    reduce_chunks<<<ncE, 1024, 0, stream>>>(rowCnt, partB, EDGES);
    scan_sums<<<1, 1024, 0, stream>>>(partB, ncE);
    scan_chunks<<<ncE, 1024, 0, stream>>>(rowCnt, partB, rowOff, EDGES);
    scatter_pass<<<NNZ_ / 256, 256, 0, stream>>>(he, colOff, rowOff, colCur, rowCur, colList, rowList);

    // conversions / weight transposes (fp16 generator+classifier path)
    conv_x<<<(NODES * FDIM + 255) / 256, 256, 0, stream>>>(x, xb, xh, NODES * FDIM);
    conv_f16<<<(512 * FDIM + 255) / 256, 256, 0, stream>>>(ge, geh, 512 * FDIM);
    transpose_f16<<<(384 * 512 + 255) / 256, 256, 0, stream>>>(g_w1, gw1t, 384, 512);
    transpose_f16<<<(512 * 128 + 255) / 256, 256, 0, stream>>>(g_w2, gw2t, 512, 128);
    transpose_f16<<<(256 * 128 + 255) / 256, 256, 0, stream>>>(cl_w1, clw1t, 256, 128);

    // generator split tables: gc = ge@W[256:384]; xag = x@W[0:128] + gc[batch] + b1; xb2 = x@W[128:256]
    xw_f16<384, false><<<dim3(512 / 64, 4), 256, 0, stream>>>(geh, gw1t + 256, gc, nullptr, nullptr, nullptr);
    xw_f16<384, true><<<dim3(NODES / 64, 4), 256, 0, stream>>>(xh, gw1t, xag, gc, batch, g_b1);
    xw_f16<384, false><<<dim3(NODES / 64, 4), 256, 0, stream>>>(xh, gw1t + 128, xb2, nullptr, nullptr, nullptr);

    // conv1 (linear-commuted): oe1 = Binv ⊙ (agg1 @ c1_w)   [NODES,256] bf16
    col_gather_x<<<NODES, 128, 0, stream>>>(xb, ei, colOff, colList, agg);
    gemm_node<256, 256, true><<<dim3(NODES / 64, 4), 256, 0, stream>>>(agg, c1_w, Binv, oe1b);

    // conv2: er materialized, flat col-aggregation, oe2 = Binv ⊙ (agg2 @ c2_w)
    er_k<<<EDGES, 128, 0, stream>>>(oe1b, rowOff, rowList, D, c1_b, er);
    col_agg_er<<<NODES, 128, 0, stream>>>(er, colOff, colList, agg);
    gemm_node<256, 128, true><<<dim3(NODES / 64, 2), 256, 0, stream>>>(agg, c2_w, Binv, oe2);

    // fused generator-L2 + classifier -> out
    gencls_mfma<<<EDGES / 64, 256, 0, stream>>>(xag, xb2, gw2t, g_b2, geh, attn, clw1t, cl_b1,
                                                cl_w2, cl_b2, c2_b, oe2, ei, batch,
                                                rowOff, rowList, D, out);
}

// Round 13
// 766.659 us; speedup vs baseline: 1.2234x; 1.2234x over previous
//
#include <hip/hip_runtime.h>
#include <hip/hip_bf16.h>
#include <hip/hip_fp16.h>

#define NODES  16000
#define FDIM   128
#define EDGES  256000
#define NNZ_   512000

typedef __attribute__((ext_vector_type(8))) short bf16x8;
typedef __attribute__((ext_vector_type(8))) _Float16 f16x8;
typedef __attribute__((ext_vector_type(4))) float f32x4;

__device__ __forceinline__ float sigmoidf_(float z) { return 1.f / (1.f + __expf(-z)); }
__device__ __forceinline__ float bflo(unsigned u) { return __uint_as_float(u << 16); }
__device__ __forceinline__ float bfhi(unsigned u) { return __uint_as_float(u & 0xffff0000u); }
__device__ __forceinline__ unsigned pack2(float lo, float hi) {
    __hip_bfloat162 h;
    h.x = __float2bfloat16(lo);
    h.y = __float2bfloat16(hi);
    return *(unsigned*)&h;
}
__device__ __forceinline__ unsigned pk_add_f16(unsigned a, unsigned b) {
    unsigned r; asm("v_pk_add_f16 %0, %1, %2" : "=v"(r) : "v"(a), "v"(b)); return r;
}
__device__ __forceinline__ unsigned pk_relu_f16(unsigned a) {
    unsigned r; asm("v_pk_max_f16 %0, %1, %2" : "=v"(r) : "v"(a), "v"(0u)); return r;
}
__device__ __forceinline__ unsigned pkh(float lo, float hi) {
    __half2 h = __floats2half2_rn(lo, hi);
    return *(unsigned*)&h;
}
__device__ __forceinline__ float2 h2f2(unsigned u) {
    return __half22float2(*(__half2*)&u);
}

// ---------------- HyperWeight ----------------
__global__ __launch_bounds__(128) void hyperweight_k(
    const float* __restrict__ x, const float* __restrict__ ge, const int* __restrict__ batch,
    const float* __restrict__ w1, const float* __restrict__ b1,
    const float* __restrict__ w2, const float* __restrict__ b2, float* __restrict__ node_w)
{
    __shared__ float a[8][256];
    __shared__ float red[128];
    const int t = threadIdx.x;
    const int nb = blockIdx.x * 8;
    for (int u = 0; u < 8; ++u) {
        int n = nb + u;
        a[u][t]       = x[(size_t)n * FDIM + t];
        a[u][128 + t] = ge[(size_t)batch[n] * FDIM + t];
    }
    __syncthreads();
    float acc[8] = {0,0,0,0,0,0,0,0};
    for (int k = 0; k < 256; ++k) {
        float wv = w1[k * 128 + t];
        #pragma unroll
        for (int u = 0; u < 8; ++u) acc[u] += a[u][k] * wv;
    }
    const float wv2 = w2[t];
    for (int u = 0; u < 8; ++u) {
        float h = fmaxf(acc[u] + b1[t], 0.f);
        red[t] = h * wv2;
        __syncthreads();
        for (int s2 = 64; s2 > 0; s2 >>= 1) {
            if (t < s2) red[t] += red[t + s2];
            __syncthreads();
        }
        if (t == 0) node_w[nb + u] = sigmoidf_(red[0] + b2[0]);
        __syncthreads();
    }
}

// ---------------- incidence pass ----------------
__global__ void incidence_pass(const int* __restrict__ he, const float* __restrict__ node_w,
                               float* __restrict__ D, int* __restrict__ Bcnt, int* __restrict__ rowCnt)
{
    int i = blockIdx.x * 256 + threadIdx.x;
    if (i >= NNZ_) return;
    int hr = he[i];
    int hc = he[NNZ_ + i];
    int hc2 = he[NNZ_ + hc];              // repo quirk: w = node_w[hcol[hcol[i]]]
    atomicAdd(&D[hr], node_w[hc2]);
    atomicAdd(&Bcnt[hc], 1);
    atomicAdd(&rowCnt[hr], 1);
}

// fused: Dinv (edges) + Binv (nodes)
__global__ void inv_k(float* __restrict__ D, const int* __restrict__ Bcnt, float* __restrict__ Binv) {
    int i = blockIdx.x * 256 + threadIdx.x;
    if (i < EDGES) {
        float d = D[i];
        D[i] = (d != 0.f) ? 1.f / d : 0.f;
    }
    if (i < NODES) {
        int c = Bcnt[i];
        Binv[i] = c ? 1.f / (float)c : 0.f;
    }
}

// ---------------- exclusive scan (3-kernel) ----------------
__global__ __launch_bounds__(1024) void reduce_chunks(const int* __restrict__ in, int* __restrict__ part, int n) {
    __shared__ int s[1024];
    int t = threadIdx.x, g = blockIdx.x * 1024 + t;
    s[t] = (g < n) ? in[g] : 0;
    __syncthreads();
    for (int d = 512; d > 0; d >>= 1) {
        if (t < d) s[t] += s[t + d];
        __syncthreads();
    }
    if (t == 0) part[blockIdx.x] = s[0];
}
__global__ __launch_bounds__(1024) void scan_sums(int* __restrict__ part, int nc) {
    __shared__ int s[1024];
    int t = threadIdx.x;
    int v = (t < nc) ? part[t] : 0;
    s[t] = v;
    __syncthreads();
    for (int d = 1; d < 1024; d <<= 1) {
        int tv = (t >= d) ? s[t - d] : 0;
        __syncthreads();
        s[t] += tv;
        __syncthreads();
    }
    if (t < nc) part[t] = s[t] - v;     // exclusive
}
__global__ __launch_bounds__(1024) void scan_chunks(const int* __restrict__ in, const int* __restrict__ part,
                                                    int* __restrict__ out, int n) {
    __shared__ int s[1024];
    int t = threadIdx.x, g = blockIdx.x * 1024 + t;
    int v = (g < n) ? in[g] : 0;
    s[t] = v;
    __syncthreads();
    for (int d = 1; d < 1024; d <<= 1) {
        int tv = (t >= d) ? s[t - d] : 0;
        __syncthreads();
        s[t] += tv;
        __syncthreads();
    }
    int excl = s[t] - v + part[blockIdx.x];
    if (g < n) out[g] = excl;
    if (g == n - 1) out[n] = excl + v;
}

// ---------------- scatter into CSR lists ----------------
__global__ void scatter_pass(const int* __restrict__ he, const int* __restrict__ colOff, const int* __restrict__ rowOff,
                             int* __restrict__ colCur, int* __restrict__ rowCur,
                             int* __restrict__ colList, int* __restrict__ rowList)
{
    int i = blockIdx.x * 256 + threadIdx.x;
    if (i >= NNZ_) return;
    int hr = he[i];
    int hc = he[NNZ_ + i];
    int p = colOff[hc] + atomicAdd(&colCur[hc], 1);
    colList[p] = hr;
    int q = rowOff[hr] + atomicAdd(&rowCur[hr], 1);
    rowList[q] = hc;
}

// ---------------- conversion helpers ----------------
__global__ void conv_x(const float* __restrict__ in, __hip_bfloat16* __restrict__ ob,
                       _Float16* __restrict__ oh, int n) {
    int i = blockIdx.x * 256 + threadIdx.x;
    if (i < n) { float v = in[i]; ob[i] = __float2bfloat16(v); oh[i] = (_Float16)v; }
}
__global__ void conv_f16(const float* __restrict__ in, _Float16* __restrict__ out, int n) {
    int i = blockIdx.x * 256 + threadIdx.x;
    if (i < n) out[i] = (_Float16)in[i];
}
// in [K][N] fp32 -> out [N][K] fp16
__global__ void transpose_f16(const float* __restrict__ in, _Float16* __restrict__ out, int K, int N) {
    int i = blockIdx.x * 256 + threadIdx.x;
    if (i >= K * N) return;
    int n = i / K, k = i - n * K;
    out[i] = (_Float16)in[k * N + n];
}
// in [K][N] fp32 row-major -> out [K/32][N][32] fp16 (MFMA B-fragment order)
__global__ void prepack_frag(const float* __restrict__ in, _Float16* __restrict__ out, int K, int N) {
    int i = blockIdx.x * 256 + threadIdx.x;
    if (i >= K * N) return;
    int k = i / N, n = i - k * N;
    out[((size_t)(k >> 5) * N + n) * 32 + (k & 31)] = (_Float16)in[i];
}

// ---------------- agg1[n,256] = sum over edges r in col(n) of [xb[ei0[r]] | xb[ei1[r]]] ----
__global__ __launch_bounds__(128) void col_gather_x(
    const __hip_bfloat16* __restrict__ xb, const int* __restrict__ ei,
    const int* __restrict__ colOff, const int* __restrict__ colList, float* __restrict__ agg)
{
    int n = blockIdx.x;
    int t = threadIdx.x;
    int base = (t < 64) ? 0 : EDGES;
    int f = t & 63;
    const unsigned* x32 = (const unsigned*)xb;
    int s = colOff[n], e = colOff[n + 1];
    float vx = 0.f, vy = 0.f;
    int j = s;
    for (; j + 3 < e; j += 4) {
        int r0 = colList[j], r1 = colList[j + 1], r2 = colList[j + 2], r3 = colList[j + 3];
        unsigned q0 = x32[(size_t)ei[base + r0] * 64 + f];
        unsigned q1 = x32[(size_t)ei[base + r1] * 64 + f];
        unsigned q2 = x32[(size_t)ei[base + r2] * 64 + f];
        unsigned q3 = x32[(size_t)ei[base + r3] * 64 + f];
        vx += bflo(q0) + bflo(q1) + bflo(q2) + bflo(q3);
        vy += bfhi(q0) + bfhi(q1) + bfhi(q2) + bfhi(q3);
    }
    for (; j < e; ++j) {
        unsigned q0 = x32[(size_t)ei[base + colList[j]] * 64 + f];
        vx += bflo(q0); vy += bfhi(q0);
    }
    int ob = (t < 64) ? 0 : 128;
    float2 o = make_float2(vx, vy);
    *(float2*)(agg + (size_t)n * 256 + ob + 2 * f) = o;
}

// ---------------- er[r,256] (bf16) = sigmoid(Dinv[r]*rowsum(oe1) + c1_b) ----------------
__global__ __launch_bounds__(128) void er_k(
    const __hip_bfloat16* __restrict__ oe1, const int* __restrict__ rowOff,
    const int* __restrict__ rowList, const float* __restrict__ Dinv,
    const float* __restrict__ c1b, __hip_bfloat16* __restrict__ er)
{
    int r = blockIdx.x;
    int t = threadIdx.x;
    int s = rowOff[r], e = rowOff[r + 1];
    const unsigned* o32 = (const unsigned*)oe1;
    float vx = 0.f, vy = 0.f;
    int j = s;
    for (; j + 1 < e; j += 2) {
        unsigned q0 = o32[(size_t)rowList[j] * 128 + t];
        unsigned q1 = o32[(size_t)rowList[j + 1] * 128 + t];
        vx += bflo(q0) + bflo(q1);
        vy += bfhi(q0) + bfhi(q1);
    }
    if (j < e) {
        unsigned q0 = o32[(size_t)rowList[j] * 128 + t];
        vx += bflo(q0); vy += bfhi(q0);
    }
    float dv = Dinv[r];
    *(unsigned*)(er + (size_t)r * 256 + 2 * t) =
        pack2(sigmoidf_(dv * vx + c1b[2 * t]), sigmoidf_(dv * vy + c1b[2 * t + 1]));
}

// ---------------- agg2[n,256] = sum over r in col(n) of er[r] ----------------
__global__ __launch_bounds__(128) void col_agg_er(
    const __hip_bfloat16* __restrict__ er, const int* __restrict__ colOff,
    const int* __restrict__ colList, float* __restrict__ agg)
{
    int n = blockIdx.x;
    int t = threadIdx.x;
    const unsigned* e32 = (const unsigned*)er;
    int s = colOff[n], e = colOff[n + 1];
    float vx = 0.f, vy = 0.f;
    int j = s;
    for (; j + 3 < e; j += 4) {
        unsigned q0 = e32[(size_t)colList[j]     * 128 + t];
        unsigned q1 = e32[(size_t)colList[j + 1] * 128 + t];
        unsigned q2 = e32[(size_t)colList[j + 2] * 128 + t];
        unsigned q3 = e32[(size_t)colList[j + 3] * 128 + t];
        vx += bflo(q0) + bflo(q1) + bflo(q2) + bflo(q3);
        vy += bfhi(q0) + bfhi(q1) + bfhi(q2) + bfhi(q3);
    }
    for (; j < e; ++j) {
        unsigned q0 = e32[(size_t)colList[j] * 128 + t];
        vx += bflo(q0); vy += bfhi(q0);
    }
    float2 o = make_float2(vx, vy);
    *(float2*)(agg + (size_t)n * 256 + 2 * t) = o;
}

// ---------------- node-rows fp32 GEMM: C = rowscale ⊙ (A @ B) ----------------
template<int K, int NN, bool OB16>
__global__ __launch_bounds__(256) void gemm_node(
    const float* __restrict__ A, const float* __restrict__ B,
    const float* __restrict__ rowscale, void* __restrict__ C)
{
    __shared__ float As[16][68];
    __shared__ float Bs[16][68];
    const int tid = threadIdx.x;
    const int m0 = blockIdx.x * 64, n0 = blockIdx.y * 64;
    const int la_k = tid & 15, la_m = tid >> 4;
    const int lb_n = tid & 63, lb_k = tid >> 6;
    const int tn = tid & 15, tm = tid >> 4;
    float acc[4][4] = {};
    for (int k0 = 0; k0 < K; k0 += 16) {
        #pragma unroll
        for (int r = 0; r < 4; ++r)
            As[la_k][la_m + 16 * r] = A[(size_t)(m0 + la_m + 16 * r) * K + k0 + la_k];
        #pragma unroll
        for (int r = 0; r < 4; ++r)
            Bs[lb_k + 4 * r][lb_n] = B[(size_t)(k0 + lb_k + 4 * r) * NN + n0 + lb_n];
        __syncthreads();
        #pragma unroll
        for (int kk = 0; kk < 16; ++kk) {
            float4 av = *(const float4*)&As[kk][tm * 4];
            float4 bv = *(const float4*)&Bs[kk][tn * 4];
            float am[4] = {av.x, av.y, av.z, av.w};
            float bn[4] = {bv.x, bv.y, bv.z, bv.w};
            #pragma unroll
            for (int i = 0; i < 4; ++i)
                #pragma unroll
                for (int j = 0; j < 4; ++j)
                    acc[i][j] += am[i] * bn[j];
        }
        __syncthreads();
    }
    #pragma unroll
    for (int i = 0; i < 4; ++i) {
        int m = m0 + tm * 4 + i;
        float rs = rowscale[m];
        if constexpr (OB16) {
            __hip_bfloat16* Cp = (__hip_bfloat16*)C + (size_t)m * NN + n0 + tn * 4;
            #pragma unroll
            for (int j = 0; j < 4; ++j) Cp[j] = __float2bfloat16(rs * acc[i][j]);
        } else {
            float4 o = make_float4(rs * acc[i][0], rs * acc[i][1], rs * acc[i][2], rs * acc[i][3]);
            *(float4*)((float*)C + (size_t)m * NN + n0 + tn * 4) = o;
        }
    }
}

// ---------------- fp16 MFMA GEMM, 64x128 tile: dst[M][512] (optionally + gc[batch]+b1) ------
template<int LDB, bool XAG>
__global__ __launch_bounds__(256) void xw_f16(
    const _Float16* __restrict__ A, const _Float16* __restrict__ Bt, _Float16* __restrict__ dst,
    const _Float16* __restrict__ gct, const int* __restrict__ batch, const float* __restrict__ bias)
{
    __shared__ __align__(16) _Float16 As[64][40];
    __shared__ __align__(16) _Float16 Bs[128][40];
    const int tid = threadIdx.x;
    const int m0 = blockIdx.x * 64, n0 = blockIdx.y * 128;
    const int wave = tid >> 6, lane = tid & 63;
    const int wr = wave >> 1, wc = wave & 1;
    const int srow = tid >> 2, kseg = (tid & 3) * 8;
    const int nr = tid >> 1, kb = (tid & 1) * 16;
    const int fr = lane & 15, krow = (lane >> 4) * 8, rq = lane >> 4;

    f32x4 acc[2][4] = {};
    for (int k0 = 0; k0 < 128; k0 += 32) {
        *(uint4*)&As[srow][kseg] = *(const uint4*)(A + (size_t)(m0 + srow) * 128 + k0 + kseg);
        *(uint4*)&Bs[nr][kb]     = *(const uint4*)(Bt + (size_t)(n0 + nr) * LDB + k0 + kb);
        *(uint4*)&Bs[nr][kb + 8] = *(const uint4*)(Bt + (size_t)(n0 + nr) * LDB + k0 + kb + 8);
        __syncthreads();
        f16x8 af[2], bf[4];
        #pragma unroll
        for (int i = 0; i < 2; ++i) af[i] = *(const f16x8*)&As[wr * 32 + i * 16 + fr][krow];
        #pragma unroll
        for (int j = 0; j < 4; ++j) bf[j] = *(const f16x8*)&Bs[wc * 64 + j * 16 + fr][krow];
        #pragma unroll
        for (int i = 0; i < 2; ++i)
            #pragma unroll
            for (int j = 0; j < 4; ++j)
                acc[i][j] = __builtin_amdgcn_mfma_f32_16x16x32_f16(af[i], bf[j], acc[i][j], 0, 0, 0);
        __syncthreads();
    }
    #pragma unroll
    for (int i = 0; i < 2; ++i)
        #pragma unroll
        for (int j = 0; j < 4; ++j) {
            int col = n0 + wc * 64 + j * 16 + fr;
            #pragma unroll
            for (int r = 0; r < 4; ++r) {
                int row = m0 + wr * 32 + i * 16 + rq * 4 + r;
                float v = acc[i][j][r];
                if constexpr (XAG)
                    v += (float)gct[(size_t)batch[row] * 512 + col] + bias[col];
                dst[(size_t)row * 512 + col] = (_Float16)v;
            }
        }
}

// ---------------- fused generator-L2 + classifier (staged A, prepacked register-direct B) ---
// Phase 1: xl = relu(relu(xag[col]+xb2[row]) @ W2 + g_b2) -> xlt (padded LDS)
// Phase 2: out = sigmoid( relu([a0*xl + a1*sij_inline | geh[gi]] @ W1cl + cl_b1)·w2 + cl_b2 )
__global__ __launch_bounds__(256) void gencls_mfma(
    const _Float16* __restrict__ xag, const _Float16* __restrict__ xb2,
    const _Float16* __restrict__ w2f,      // [16][128][32] fragment-packed g_w2
    const float* __restrict__ gb2,
    const _Float16* __restrict__ geh, const float* __restrict__ attn,
    const _Float16* __restrict__ w1f,      // [8][128][32] fragment-packed cl_w1
    const float* __restrict__ clb1,
    const float* __restrict__ w2, const float* __restrict__ b2, const float* __restrict__ c2b,
    const __hip_bfloat16* __restrict__ oe2,
    const int* __restrict__ ei, const int* __restrict__ batch,
    const int* __restrict__ rowOff, const int* __restrict__ rowList, const float* __restrict__ Dinv,
    float* __restrict__ out)
{
    __shared__ __align__(16) _Float16 As[64][40];
    __shared__ __align__(16) _Float16 xlt[64][136];   // padded: 2-way max on reads
    const int tid = threadIdx.x;
    const int m0 = blockIdx.x * 64;
    const int wave = tid >> 6, lane = tid & 63;
    const int wr = wave >> 1, wc = wave & 1;
    const int srow = tid >> 2, kseg = (tid & 3) * 8;
    const int fr = lane & 15, rq = lane >> 4, krow = rq * 8;

    const int eg = m0 + srow;
    const _Float16* pa = xag + (size_t)ei[eg] * 512;
    const _Float16* pb = xb2 + (size_t)ei[EDGES + eg] * 512;

    // ---- phase 1: A staged (coalesced gather), B register-direct coalesced ----
    f32x4 acc[2][4] = {};
    for (int k0 = 0; k0 < 512; k0 += 32) {
        int kg = k0 + kseg;
        uint4 ua = *(const uint4*)(pa + kg);
        uint4 ub = *(const uint4*)(pb + kg);
        // B fragment loads (independent of LDS) — issue before barrier
        const _Float16* pB = w2f + ((size_t)(k0 >> 5) * 128 + wc * 64 + fr) * 32 + krow;
        uint4 bfr[4];
        #pragma unroll
        for (int j = 0; j < 4; ++j) bfr[j] = *(const uint4*)(pB + j * 512);
        uint4 av;
        av.x = pk_relu_f16(pk_add_f16(ua.x, ub.x));
        av.y = pk_relu_f16(pk_add_f16(ua.y, ub.y));
        av.z = pk_relu_f16(pk_add_f16(ua.z, ub.z));
        av.w = pk_relu_f16(pk_add_f16(ua.w, ub.w));
        *(uint4*)&As[srow][kseg] = av;
        __syncthreads();
        f16x8 af0 = *(const f16x8*)&As[wr * 32 + fr][krow];
        f16x8 af1 = *(const f16x8*)&As[wr * 32 + 16 + fr][krow];
        #pragma unroll
        for (int j = 0; j < 4; ++j) {
            f16x8 bf = *(const f16x8*)&bfr[j];
            acc[0][j] = __builtin_amdgcn_mfma_f32_16x16x32_f16(af0, bf, acc[0][j], 0, 0, 0);
            acc[1][j] = __builtin_amdgcn_mfma_f32_16x16x32_f16(af1, bf, acc[1][j], 0, 0, 0);
        }
        __syncthreads();
    }
    // xl tile -> padded LDS (bias + relu), C-layout scatter
    #pragma unroll
    for (int i = 0; i < 2; ++i)
        #pragma unroll
        for (int j = 0; j < 4; ++j) {
            int col = wc * 64 + j * 16 + fr;
            float bc = gb2[col];
            #pragma unroll
            for (int r = 0; r < 4; ++r) {
                int row = wr * 32 + i * 16 + rq * 4 + r;
                xlt[row][col] = (_Float16)fmaxf(acc[i][j][r] + bc, 0.f);
            }
        }
    __syncthreads();

    // ---- phase 2: fully register-direct (A per-lane, B prepacked coalesced), no barriers ----
    const float a0 = attn[0], a1 = attn[1];
    const int row_l = wave * 16 + fr;
    const int e2 = m0 + row_l;
    const int gi = batch[ei[e2]];
    const int rs = rowOff[e2], re = rowOff[e2 + 1];
    const float dv = Dinv[e2];

    f32x4 acc2[8] = {};
    for (int it = 0; it < 8; ++it) {
        int kg = it * 32 + krow;
        f16x8 af;
        if (it < 4) {
            uint4 u = *(const uint4*)&xlt[row_l][kg];
            float s0 = 0.f, s1 = 0.f, s2 = 0.f, s3 = 0.f, s4 = 0.f, s5 = 0.f, s6 = 0.f, s7 = 0.f;
            for (int q = rs; q < re; ++q) {
                uint4 o = *(const uint4*)(oe2 + (size_t)rowList[q] * 128 + kg);
                s0 += bflo(o.x); s1 += bfhi(o.x); s2 += bflo(o.y); s3 += bfhi(o.y);
                s4 += bflo(o.z); s5 += bfhi(o.z); s6 += bflo(o.w); s7 += bfhi(o.w);
            }
            float4 c0 = *(const float4*)(c2b + kg);
            float4 c1 = *(const float4*)(c2b + kg + 4);
            float2 g0 = h2f2(u.x), g1 = h2f2(u.y), g2 = h2f2(u.z), g3 = h2f2(u.w);
            uint4 av;
            av.x = pkh(a0 * g0.x + a1 * sigmoidf_(dv * s0 + c0.x),
                       a0 * g0.y + a1 * sigmoidf_(dv * s1 + c0.y));
            av.y = pkh(a0 * g1.x + a1 * sigmoidf_(dv * s2 + c0.z),
                       a0 * g1.y + a1 * sigmoidf_(dv * s3 + c0.w));
            av.z = pkh(a0 * g2.x + a1 * sigmoidf_(dv * s4 + c1.x),
                       a0 * g2.y + a1 * sigmoidf_(dv * s5 + c1.y));
            av.w = pkh(a0 * g3.x + a1 * sigmoidf_(dv * s6 + c1.z),
                       a0 * g3.y + a1 * sigmoidf_(dv * s7 + c1.w));
            af = *(f16x8*)&av;
        } else {
            af = *(const f16x8*)(geh + (size_t)gi * 128 + kg - 128);
        }
        const _Float16* pB2 = w1f + ((size_t)it * 128 + fr) * 32 + krow;
        #pragma unroll
        for (int j = 0; j < 8; ++j) {
            f16x8 bf = *(const f16x8*)(pB2 + j * 512);
            acc2[j] = __builtin_amdgcn_mfma_f32_16x16x32_f16(af, bf, acc2[j], 0, 0, 0);
        }
    }
    // epilogue: relu(+clb1), dot w2, 16-lane reduce, sigmoid
    float rsum[4] = {0.f, 0.f, 0.f, 0.f};
    #pragma unroll
    for (int j = 0; j < 8; ++j) {
        int colg = j * 16 + fr;
        float bc = clb1[colg];
        float wv = w2[colg];
        #pragma unroll
        for (int r = 0; r < 4; ++r)
            rsum[r] += fmaxf(acc2[j][r] + bc, 0.f) * wv;
    }
    #pragma unroll
    for (int m = 1; m < 16; m <<= 1) {
        #pragma unroll
        for (int r = 0; r < 4; ++r) rsum[r] += __shfl_xor(rsum[r], m, 64);
    }
    if (fr == 0) {
        float bb = b2[0];
        #pragma unroll
        for (int r = 0; r < 4; ++r)
            out[m0 + wave * 16 + rq * 4 + r] = sigmoidf_(rsum[r] + bb);
    }
}

// =======================================================================================
extern "C" void kernel_launch(void* const* d_in, const int* in_sizes, int n_in,
                              void* d_out, int out_size, void* d_ws, size_t ws_size,
                              hipStream_t stream)
{
    const float* x     = (const float*)d_in[0];
    const float* ge    = (const float*)d_in[1];
    const int*   ei    = (const int*)d_in[2];
    const int*   batch = (const int*)d_in[4];
    const int*   he    = (const int*)d_in[5];
    const float* hw_w1 = (const float*)d_in[6];
    const float* hw_b1 = (const float*)d_in[7];
    const float* hw_w2 = (const float*)d_in[8];
    const float* hw_b2 = (const float*)d_in[9];
    const float* c1_w  = (const float*)d_in[10];
    const float* c1_b  = (const float*)d_in[11];
    const float* c2_w  = (const float*)d_in[12];
    const float* c2_b  = (const float*)d_in[13];
    const float* g_w1  = (const float*)d_in[14];
    const float* g_b1  = (const float*)d_in[15];
    const float* g_w2  = (const float*)d_in[16];
    const float* g_b2  = (const float*)d_in[17];
    const float* cl_w1 = (const float*)d_in[18];
    const float* cl_b1 = (const float*)d_in[19];
    const float* cl_w2 = (const float*)d_in[20];
    const float* cl_b2 = (const float*)d_in[21];
    const float* attn  = (const float*)d_in[22];
    float* out = (float*)d_out;

    char* ws = (char*)d_ws;
    size_t off = 0;
    auto alloc = [&](size_t nb) -> void* {
        off = (off + 255) & ~(size_t)255;
        void* p = ws + off;
        off += nb;
        return p;
    };
    // ---- zero region (one memset): D, Bcnt, rowCnt, colCur, rowCur ----
    float* D      = (float*)alloc((size_t)EDGES * 4);   // becomes Dinv in place
    int*   Bcnt   = (int*)  alloc((size_t)NODES * 4);
    int*   rowCnt = (int*)  alloc((size_t)EDGES * 4);
    int*   colCur = (int*)  alloc((size_t)NODES * 4);
    int*   rowCur = (int*)  alloc((size_t)EDGES * 4);
    size_t zero_end = off;
    // ---- other small arrays ----
    float* node_w = (float*)alloc((size_t)NODES * 4);
    float* Binv   = (float*)alloc((size_t)NODES * 4);
    int*   colOff = (int*)  alloc((size_t)(NODES + 1) * 4);
    int*   rowOff = (int*)  alloc((size_t)(EDGES + 1) * 4);
    int*   colList= (int*)  alloc((size_t)NNZ_ * 4);
    int*   rowList= (int*)  alloc((size_t)NNZ_ * 4);
    int*   partA  = (int*)  alloc(1024 * 4);
    int*   partB  = (int*)  alloc(1024 * 4);
    // dtype tables (~10 MB)
    __hip_bfloat16* xb    = (__hip_bfloat16*)alloc((size_t)NODES * FDIM * 2);
    _Float16* xh    = (_Float16*)alloc((size_t)NODES * FDIM * 2);
    _Float16* geh   = (_Float16*)alloc((size_t)512 * FDIM * 2);
    _Float16* gw1t  = (_Float16*)alloc((size_t)512 * 384 * 2);
    _Float16* w2f   = (_Float16*)alloc((size_t)16 * 128 * 32 * 2);   // fragment-packed g_w2
    _Float16* w1f   = (_Float16*)alloc((size_t)8 * 128 * 32 * 2);    // fragment-packed cl_w1
    // generator split tables (~33.5 MB)
    _Float16* xag   = (_Float16*)alloc((size_t)NODES * 512 * 2);
    _Float16* xb2   = (_Float16*)alloc((size_t)NODES * 512 * 2);
    _Float16* gc    = (_Float16*)alloc((size_t)512 * 512 * 2);
    // big buffers
    float* agg  = (float*)alloc((size_t)NODES * 256 * 4);                    // 16.4 MB
    __hip_bfloat16* oe1b = (__hip_bfloat16*)alloc((size_t)NODES * 256 * 2);  // 8.2 MB
    __hip_bfloat16* oe2  = (__hip_bfloat16*)alloc((size_t)NODES * 128 * 2);  // 4.1 MB
    __hip_bfloat16* er   = (__hip_bfloat16*)alloc((size_t)EDGES * 256 * 2);  // 131 MB

    hipMemsetAsync(D, 0, zero_end, stream);   // zeroes D..rowCur (incl. align pads)

    hyperweight_k<<<NODES / 8, 128, 0, stream>>>(x, ge, batch, hw_w1, hw_b1, hw_w2, hw_b2, node_w);
    incidence_pass<<<NNZ_ / 256, 256, 0, stream>>>(he, node_w, D, Bcnt, rowCnt);
    inv_k<<<EDGES / 256, 256, 0, stream>>>(D, Bcnt, Binv);

    const int ncN = (NODES + 1023) / 1024;
    const int ncE = (EDGES + 1023) / 1024;
    reduce_chunks<<<ncN, 1024, 0, stream>>>(Bcnt, partA, NODES);
    scan_sums<<<1, 1024, 0, stream>>>(partA, ncN);
    scan_chunks<<<ncN, 1024, 0, stream>>>(Bcnt, partA, colOff, NODES);
    reduce_chunks<<<ncE, 1024, 0, stream>>>(rowCnt, partB, EDGES);
    scan_sums<<<1, 1024, 0, stream>>>(partB, ncE);
    scan_chunks<<<ncE, 1024, 0, stream>>>(rowCnt, partB, rowOff, EDGES);
    scatter_pass<<<NNZ_ / 256, 256, 0, stream>>>(he, colOff, rowOff, colCur, rowCur, colList, rowList);

    // conversions / weight transposes / fragment prepacks (fp16 generator+classifier path)
    conv_x<<<(NODES * FDIM + 255) / 256, 256, 0, stream>>>(x, xb, xh, NODES * FDIM);
    conv_f16<<<(512 * FDIM + 255) / 256, 256, 0, stream>>>(ge, geh, 512 * FDIM);
    transpose_f16<<<(384 * 512 + 255) / 256, 256, 0, stream>>>(g_w1, gw1t, 384, 512);
    prepack_frag<<<(512 * 128 + 255) / 256, 256, 0, stream>>>(g_w2, w2f, 512, 128);
    prepack_frag<<<(256 * 128 + 255) / 256, 256, 0, stream>>>(cl_w1, w1f, 256, 128);

    // generator split tables: gc = ge@W[256:384]; xag = x@W[0:128] + gc[batch] + b1; xb2 = x@W[128:256]
    xw_f16<384, false><<<dim3(512 / 64, 4), 256, 0, stream>>>(geh, gw1t + 256, gc, nullptr, nullptr, nullptr);
    xw_f16<384, true><<<dim3(NODES / 64, 4), 256, 0, stream>>>(xh, gw1t, xag, gc, batch, g_b1);
    xw_f16<384, false><<<dim3(NODES / 64, 4), 256, 0, stream>>>(xh, gw1t + 128, xb2, nullptr, nullptr, nullptr);

    // conv1 (linear-commuted): oe1 = Binv ⊙ (agg1 @ c1_w)   [NODES,256] bf16
    col_gather_x<<<NODES, 128, 0, stream>>>(xb, ei, colOff, colList, agg);
    gemm_node<256, 256, true><<<dim3(NODES / 64, 4), 256, 0, stream>>>(agg, c1_w, Binv, oe1b);

    // conv2: er materialized, flat col-aggregation, oe2 = Binv ⊙ (agg2 @ c2_w)
    er_k<<<EDGES, 128, 0, stream>>>(oe1b, rowOff, rowList, D, c1_b, er);
    col_agg_er<<<NODES, 128, 0, stream>>>(er, colOff, colList, agg);
    gemm_node<256, 128, true><<<dim3(NODES / 64, 2), 256, 0, stream>>>(agg, c2_w, Binv, oe2);

    // fused generator-L2 + classifier -> out
    gencls_mfma<<<EDGES / 64, 256, 0, stream>>>(xag, xb2, w2f, g_b2, geh, attn, w1f, cl_b1,
                                                cl_w2, cl_b2, c2_b, oe2, ei, batch,
                                                rowOff, rowList, D, out);
}

// Round 14
// 764.360 us; speedup vs baseline: 1.2271x; 1.0030x over previous
//
#include <hip/hip_runtime.h>
#include <hip/hip_bf16.h>
#include <hip/hip_fp16.h>

#define NODES  16000
#define FDIM   128
#define EDGES  256000
#define NNZ_   512000

typedef __attribute__((ext_vector_type(8))) short bf16x8;
typedef __attribute__((ext_vector_type(8))) _Float16 f16x8;
typedef __attribute__((ext_vector_type(4))) float f32x4;

__device__ __forceinline__ float sigmoidf_(float z) { return 1.f / (1.f + __expf(-z)); }
__device__ __forceinline__ float bflo(unsigned u) { return __uint_as_float(u << 16); }
__device__ __forceinline__ float bfhi(unsigned u) { return __uint_as_float(u & 0xffff0000u); }
__device__ __forceinline__ unsigned pack2(float lo, float hi) {
    __hip_bfloat162 h;
    h.x = __float2bfloat16(lo);
    h.y = __float2bfloat16(hi);
    return *(unsigned*)&h;
}
__device__ __forceinline__ unsigned pk_add_f16(unsigned a, unsigned b) {
    unsigned r; asm("v_pk_add_f16 %0, %1, %2" : "=v"(r) : "v"(a), "v"(b)); return r;
}
__device__ __forceinline__ unsigned pk_relu_f16(unsigned a) {
    unsigned r; asm("v_pk_max_f16 %0, %1, %2" : "=v"(r) : "v"(a), "v"(0u)); return r;
}
__device__ __forceinline__ unsigned pkh(float lo, float hi) {
    __half2 h = __floats2half2_rn(lo, hi);
    return *(unsigned*)&h;
}
__device__ __forceinline__ float2 h2f2(unsigned u) {
    return __half22float2(*(__half2*)&u);
}

// ---------------- HyperWeight ----------------
__global__ __launch_bounds__(128) void hyperweight_k(
    const float* __restrict__ x, const float* __restrict__ ge, const int* __restrict__ batch,
    const float* __restrict__ w1, const float* __restrict__ b1,
    const float* __restrict__ w2, const float* __restrict__ b2, float* __restrict__ node_w)
{
    __shared__ float a[8][256];
    __shared__ float red[128];
    const int t = threadIdx.x;
    const int nb = blockIdx.x * 8;
    for (int u = 0; u < 8; ++u) {
        int n = nb + u;
        a[u][t]       = x[(size_t)n * FDIM + t];
        a[u][128 + t] = ge[(size_t)batch[n] * FDIM + t];
    }
    __syncthreads();
    float acc[8] = {0,0,0,0,0,0,0,0};
    for (int k = 0; k < 256; ++k) {
        float wv = w1[k * 128 + t];
        #pragma unroll
        for (int u = 0; u < 8; ++u) acc[u] += a[u][k] * wv;
    }
    const float wv2 = w2[t];
    for (int u = 0; u < 8; ++u) {
        float h = fmaxf(acc[u] + b1[t], 0.f);
        red[t] = h * wv2;
        __syncthreads();
        for (int s2 = 64; s2 > 0; s2 >>= 1) {
            if (t < s2) red[t] += red[t + s2];
            __syncthreads();
        }
        if (t == 0) node_w[nb + u] = sigmoidf_(red[0] + b2[0]);
        __syncthreads();
    }
}

// ---------------- incidence pass ----------------
__global__ void incidence_pass(const int* __restrict__ he, const float* __restrict__ node_w,
                               float* __restrict__ D, int* __restrict__ Bcnt, int* __restrict__ rowCnt)
{
    int i = blockIdx.x * 256 + threadIdx.x;
    if (i >= NNZ_) return;
    int hr = he[i];
    int hc = he[NNZ_ + i];
    int hc2 = he[NNZ_ + hc];              // repo quirk: w = node_w[hcol[hcol[i]]]
    atomicAdd(&D[hr], node_w[hc2]);
    atomicAdd(&Bcnt[hc], 1);
    atomicAdd(&rowCnt[hr], 1);
}

// fused: Dinv (edges) + Binv (nodes) + edge-col count
__global__ void inv_k(float* __restrict__ D, const int* __restrict__ Bcnt, float* __restrict__ Binv,
                      const int* __restrict__ ei, int* __restrict__ ecnt) {
    int i = blockIdx.x * 256 + threadIdx.x;
    if (i < EDGES) {
        float d = D[i];
        D[i] = (d != 0.f) ? 1.f / d : 0.f;
        atomicAdd(&ecnt[ei[i]], 1);
    }
    if (i < NODES) {
        int c = Bcnt[i];
        Binv[i] = c ? 1.f / (float)c : 0.f;
    }
}

// ---------------- exclusive scan (3-kernel) ----------------
__global__ __launch_bounds__(1024) void reduce_chunks(const int* __restrict__ in, int* __restrict__ part, int n) {
    __shared__ int s[1024];
    int t = threadIdx.x, g = blockIdx.x * 1024 + t;
    s[t] = (g < n) ? in[g] : 0;
    __syncthreads();
    for (int d = 512; d > 0; d >>= 1) {
        if (t < d) s[t] += s[t + d];
        __syncthreads();
    }
    if (t == 0) part[blockIdx.x] = s[0];
}
__global__ __launch_bounds__(1024) void scan_sums(int* __restrict__ part, int nc) {
    __shared__ int s[1024];
    int t = threadIdx.x;
    int v = (t < nc) ? part[t] : 0;
    s[t] = v;
    __syncthreads();
    for (int d = 1; d < 1024; d <<= 1) {
        int tv = (t >= d) ? s[t - d] : 0;
        __syncthreads();
        s[t] += tv;
        __syncthreads();
    }
    if (t < nc) part[t] = s[t] - v;     // exclusive
}
__global__ __launch_bounds__(1024) void scan_chunks(const int* __restrict__ in, const int* __restrict__ part,
                                                    int* __restrict__ out, int n) {
    __shared__ int s[1024];
    int t = threadIdx.x, g = blockIdx.x * 1024 + t;
    int v = (g < n) ? in[g] : 0;
    s[t] = v;
    __syncthreads();
    for (int d = 1; d < 1024; d <<= 1) {
        int tv = (t >= d) ? s[t - d] : 0;
        __syncthreads();
        s[t] += tv;
        __syncthreads();
    }
    int excl = s[t] - v + part[blockIdx.x];
    if (g < n) out[g] = excl;
    if (g == n - 1) out[n] = excl + v;
}

// ---------------- scatter into CSR lists ----------------
__global__ void scatter_pass(const int* __restrict__ he, const int* __restrict__ colOff, const int* __restrict__ rowOff,
                             int* __restrict__ colCur, int* __restrict__ rowCur,
                             int* __restrict__ colList, int* __restrict__ rowList)
{
    int i = blockIdx.x * 256 + threadIdx.x;
    if (i >= NNZ_) return;
    int hr = he[i];
    int hc = he[NNZ_ + i];
    int p = colOff[hc] + atomicAdd(&colCur[hc], 1);
    colList[p] = hr;
    int q = rowOff[hr] + atomicAdd(&rowCur[hr], 1);
    rowList[q] = hc;
}

// ---------------- edge sort-by-col scatter: perm[pos] = e ----------------
__global__ void edge_scatter(const int* __restrict__ ei, const int* __restrict__ eoff,
                             int* __restrict__ ecur, int* __restrict__ perm)
{
    int e = blockIdx.x * 256 + threadIdx.x;
    if (e >= EDGES) return;
    int c = ei[e];
    int pos = eoff[c] + atomicAdd(&ecur[c], 1);
    perm[pos] = e;
}

// ---------------- conversion helpers ----------------
__global__ void conv_x(const float* __restrict__ in, __hip_bfloat16* __restrict__ ob,
                       _Float16* __restrict__ oh, int n) {
    int i = blockIdx.x * 256 + threadIdx.x;
    if (i < n) { float v = in[i]; ob[i] = __float2bfloat16(v); oh[i] = (_Float16)v; }
}
__global__ void conv_f16(const float* __restrict__ in, _Float16* __restrict__ out, int n) {
    int i = blockIdx.x * 256 + threadIdx.x;
    if (i < n) out[i] = (_Float16)in[i];
}
// in [K][N] fp32 -> out [N][K] fp16
__global__ void transpose_f16(const float* __restrict__ in, _Float16* __restrict__ out, int K, int N) {
    int i = blockIdx.x * 256 + threadIdx.x;
    if (i >= K * N) return;
    int n = i / K, k = i - n * K;
    out[i] = (_Float16)in[k * N + n];
}

// ---------------- agg1[n,256] = sum over edges r in col(n) of [xb[ei0[r]] | xb[ei1[r]]] ----
__global__ __launch_bounds__(128) void col_gather_x(
    const __hip_bfloat16* __restrict__ xb, const int* __restrict__ ei,
    const int* __restrict__ colOff, const int* __restrict__ colList, float* __restrict__ agg)
{
    int n = blockIdx.x;
    int t = threadIdx.x;
    int base = (t < 64) ? 0 : EDGES;
    int f = t & 63;
    const unsigned* x32 = (const unsigned*)xb;
    int s = colOff[n], e = colOff[n + 1];
    float vx = 0.f, vy = 0.f;
    int j = s;
    for (; j + 3 < e; j += 4) {
        int r0 = colList[j], r1 = colList[j + 1], r2 = colList[j + 2], r3 = colList[j + 3];
        unsigned q0 = x32[(size_t)ei[base + r0] * 64 + f];
        unsigned q1 = x32[(size_t)ei[base + r1] * 64 + f];
        unsigned q2 = x32[(size_t)ei[base + r2] * 64 + f];
        unsigned q3 = x32[(size_t)ei[base + r3] * 64 + f];
        vx += bflo(q0) + bflo(q1) + bflo(q2) + bflo(q3);
        vy += bfhi(q0) + bfhi(q1) + bfhi(q2) + bfhi(q3);
    }
    for (; j < e; ++j) {
        unsigned q0 = x32[(size_t)ei[base + colList[j]] * 64 + f];
        vx += bflo(q0); vy += bfhi(q0);
    }
    int ob = (t < 64) ? 0 : 128;
    float2 o = make_float2(vx, vy);
    *(float2*)(agg + (size_t)n * 256 + ob + 2 * f) = o;
}

// ---------------- er[r,256] (bf16) = sigmoid(Dinv[r]*rowsum(oe1) + c1_b) ----------------
__global__ __launch_bounds__(128) void er_k(
    const __hip_bfloat16* __restrict__ oe1, const int* __restrict__ rowOff,
    const int* __restrict__ rowList, const float* __restrict__ Dinv,
    const float* __restrict__ c1b, __hip_bfloat16* __restrict__ er)
{
    int r = blockIdx.x;
    int t = threadIdx.x;
    int s = rowOff[r], e = rowOff[r + 1];
    const unsigned* o32 = (const unsigned*)oe1;
    float vx = 0.f, vy = 0.f;
    int j = s;
    for (; j + 1 < e; j += 2) {
        unsigned q0 = o32[(size_t)rowList[j] * 128 + t];
        unsigned q1 = o32[(size_t)rowList[j + 1] * 128 + t];
        vx += bflo(q0) + bflo(q1);
        vy += bfhi(q0) + bfhi(q1);
    }
    if (j < e) {
        unsigned q0 = o32[(size_t)rowList[j] * 128 + t];
        vx += bflo(q0); vy += bfhi(q0);
    }
    float dv = Dinv[r];
    *(unsigned*)(er + (size_t)r * 256 + 2 * t) =
        pack2(sigmoidf_(dv * vx + c1b[2 * t]), sigmoidf_(dv * vy + c1b[2 * t + 1]));
}

// ---------------- agg2[n,256] = sum over r in col(n) of er[r] ----------------
__global__ __launch_bounds__(128) void col_agg_er(
    const __hip_bfloat16* __restrict__ er, const int* __restrict__ colOff,
    const int* __restrict__ colList, float* __restrict__ agg)
{
    int n = blockIdx.x;
    int t = threadIdx.x;
    const unsigned* e32 = (const unsigned*)er;
    int s = colOff[n], e = colOff[n + 1];
    float vx = 0.f, vy = 0.f;
    int j = s;
    for (; j + 3 < e; j += 4) {
        unsigned q0 = e32[(size_t)colList[j]     * 128 + t];
        unsigned q1 = e32[(size_t)colList[j + 1] * 128 + t];
        unsigned q2 = e32[(size_t)colList[j + 2] * 128 + t];
        unsigned q3 = e32[(size_t)colList[j + 3] * 128 + t];
        vx += bflo(q0) + bflo(q1) + bflo(q2) + bflo(q3);
        vy += bfhi(q0) + bfhi(q1) + bfhi(q2) + bfhi(q3);
    }
    for (; j < e; ++j) {
        unsigned q0 = e32[(size_t)colList[j] * 128 + t];
        vx += bflo(q0); vy += bfhi(q0);
    }
    float2 o = make_float2(vx, vy);
    *(float2*)(agg + (size_t)n * 256 + 2 * t) = o;
}

// ---------------- node-rows fp32 GEMM: C = rowscale ⊙ (A @ B) ----------------
template<int K, int NN, bool OB16>
__global__ __launch_bounds__(256) void gemm_node(
    const float* __restrict__ A, const float* __restrict__ B,
    const float* __restrict__ rowscale, void* __restrict__ C)
{
    __shared__ float As[16][68];
    __shared__ float Bs[16][68];
    const int tid = threadIdx.x;
    const int m0 = blockIdx.x * 64, n0 = blockIdx.y * 64;
    const int la_k = tid & 15, la_m = tid >> 4;
    const int lb_n = tid & 63, lb_k = tid >> 6;
    const int tn = tid & 15, tm = tid >> 4;
    float acc[4][4] = {};
    for (int k0 = 0; k0 < K; k0 += 16) {
        #pragma unroll
        for (int r = 0; r < 4; ++r)
            As[la_k][la_m + 16 * r] = A[(size_t)(m0 + la_m + 16 * r) * K + k0 + la_k];
        #pragma unroll
        for (int r = 0; r < 4; ++r)
            Bs[lb_k + 4 * r][lb_n] = B[(size_t)(k0 + lb_k + 4 * r) * NN + n0 + lb_n];
        __syncthreads();
        #pragma unroll
        for (int kk = 0; kk < 16; ++kk) {
            float4 av = *(const float4*)&As[kk][tm * 4];
            float4 bv = *(const float4*)&Bs[kk][tn * 4];
            float am[4] = {av.x, av.y, av.z, av.w};
            float bn[4] = {bv.x, bv.y, bv.z, bv.w};
            #pragma unroll
            for (int i = 0; i < 4; ++i)
                #pragma unroll
                for (int j = 0; j < 4; ++j)
                    acc[i][j] += am[i] * bn[j];
        }
        __syncthreads();
    }
    #pragma unroll
    for (int i = 0; i < 4; ++i) {
        int m = m0 + tm * 4 + i;
        float rs = rowscale[m];
        if constexpr (OB16) {
            __hip_bfloat16* Cp = (__hip_bfloat16*)C + (size_t)m * NN + n0 + tn * 4;
            #pragma unroll
            for (int j = 0; j < 4; ++j) Cp[j] = __float2bfloat16(rs * acc[i][j]);
        } else {
            float4 o = make_float4(rs * acc[i][0], rs * acc[i][1], rs * acc[i][2], rs * acc[i][3]);
            *(float4*)((float*)C + (size_t)m * NN + n0 + tn * 4) = o;
        }
    }
}

// ---------------- fp16 MFMA GEMM, 64x128 tile: dst[M][512] (optionally + gc[batch]+b1) ------
template<int LDB, bool XAG>
__global__ __launch_bounds__(256) void xw_f16(
    const _Float16* __restrict__ A, const _Float16* __restrict__ Bt, _Float16* __restrict__ dst,
    const _Float16* __restrict__ gct, const int* __restrict__ batch, const float* __restrict__ bias)
{
    __shared__ __align__(16) _Float16 As[64][40];
    __shared__ __align__(16) _Float16 Bs[128][40];
    const int tid = threadIdx.x;
    const int m0 = blockIdx.x * 64, n0 = blockIdx.y * 128;
    const int wave = tid >> 6, lane = tid & 63;
    const int wr = wave >> 1, wc = wave & 1;
    const int srow = tid >> 2, kseg = (tid & 3) * 8;
    const int nr = tid >> 1, kb = (tid & 1) * 16;
    const int fr = lane & 15, krow = (lane >> 4) * 8, rq = lane >> 4;

    f32x4 acc[2][4] = {};
    for (int k0 = 0; k0 < 128; k0 += 32) {
        *(uint4*)&As[srow][kseg] = *(const uint4*)(A + (size_t)(m0 + srow) * 128 + k0 + kseg);
        *(uint4*)&Bs[nr][kb]     = *(const uint4*)(Bt + (size_t)(n0 + nr) * LDB + k0 + kb);
        *(uint4*)&Bs[nr][kb + 8] = *(const uint4*)(Bt + (size_t)(n0 + nr) * LDB + k0 + kb + 8);
        __syncthreads();
        f16x8 af[2], bf[4];
        #pragma unroll
        for (int i = 0; i < 2; ++i) af[i] = *(const f16x8*)&As[wr * 32 + i * 16 + fr][krow];
        #pragma unroll
        for (int j = 0; j < 4; ++j) bf[j] = *(const f16x8*)&Bs[wc * 64 + j * 16 + fr][krow];
        #pragma unroll
        for (int i = 0; i < 2; ++i)
            #pragma unroll
            for (int j = 0; j < 4; ++j)
                acc[i][j] = __builtin_amdgcn_mfma_f32_16x16x32_f16(af[i], bf[j], acc[i][j], 0, 0, 0);
        __syncthreads();
    }
    #pragma unroll
    for (int i = 0; i < 2; ++i)
        #pragma unroll
        for (int j = 0; j < 4; ++j) {
            int col = n0 + wc * 64 + j * 16 + fr;
            #pragma unroll
            for (int r = 0; r < 4; ++r) {
                int row = m0 + wr * 32 + i * 16 + rq * 4 + r;
                float v = acc[i][j][r];
                if constexpr (XAG)
                    v += (float)gct[(size_t)batch[row] * 512 + col] + bias[col];
                dst[(size_t)row * 512 + col] = (_Float16)v;
            }
        }
}

// ---------------- fused generator-L2 + classifier (round-10 staged structure + edge sort) ---
// Edges processed in col-sorted order via perm[] for gather locality.
__global__ __launch_bounds__(256) void gencls_mfma(
    const _Float16* __restrict__ xag, const _Float16* __restrict__ xb2,
    const _Float16* __restrict__ gw2t, const float* __restrict__ gb2,
    const _Float16* __restrict__ geh, const float* __restrict__ attn,
    const _Float16* __restrict__ clw1t, const float* __restrict__ clb1,
    const float* __restrict__ w2, const float* __restrict__ b2, const float* __restrict__ c2b,
    const __hip_bfloat16* __restrict__ oe2,
    const int* __restrict__ ei, const int* __restrict__ batch,
    const int* __restrict__ rowOff, const int* __restrict__ rowList, const float* __restrict__ Dinv,
    const int* __restrict__ perm,
    float* __restrict__ out)
{
    __shared__ __align__(16) _Float16 As[64][40];
    __shared__ __align__(16) _Float16 Bs[128][40];
    __shared__ __align__(16) _Float16 xlt[64][136];   // 272B rows: 16B-aligned, <=2-way conflicts
    const int tid = threadIdx.x;
    const int m0 = blockIdx.x * 64;
    const int wave = tid >> 6, lane = tid & 63;
    const int wr = wave >> 1, wc = wave & 1;
    const int srow = tid >> 2, kseg = (tid & 3) * 8;
    const int nr = tid >> 1, kb = (tid & 1) * 16;
    const int fr = lane & 15, rq = lane >> 4, krow = rq * 8;

    const int eg = perm[m0 + srow];
    const int cnode = ei[eg];
    const _Float16* pa = xag + (size_t)cnode * 512;
    const _Float16* pb = xb2 + (size_t)ei[EDGES + eg] * 512;
    const int gi = batch[cnode];
    const int rs = rowOff[eg], re = rowOff[eg + 1];
    const float dv = Dinv[eg];

    // ---- phase 1: generator L2 GEMM (K=512), staged A and B ----
    f32x4 acc[2][4] = {};
    for (int k0 = 0; k0 < 512; k0 += 32) {
        int kg = k0 + kseg;
        uint4 ua = *(const uint4*)(pa + kg);
        uint4 ub = *(const uint4*)(pb + kg);
        uint4 av;
        av.x = pk_relu_f16(pk_add_f16(ua.x, ub.x));
        av.y = pk_relu_f16(pk_add_f16(ua.y, ub.y));
        av.z = pk_relu_f16(pk_add_f16(ua.z, ub.z));
        av.w = pk_relu_f16(pk_add_f16(ua.w, ub.w));
        *(uint4*)&As[srow][kseg] = av;
        *(uint4*)&Bs[nr][kb]     = *(const uint4*)(gw2t + (size_t)nr * 512 + k0 + kb);
        *(uint4*)&Bs[nr][kb + 8] = *(const uint4*)(gw2t + (size_t)nr * 512 + k0 + kb + 8);
        __syncthreads();
        f16x8 af[2], bf[4];
        #pragma unroll
        for (int i = 0; i < 2; ++i) af[i] = *(const f16x8*)&As[wr * 32 + i * 16 + fr][krow];
        #pragma unroll
        for (int j = 0; j < 4; ++j) bf[j] = *(const f16x8*)&Bs[wc * 64 + j * 16 + fr][krow];
        #pragma unroll
        for (int i = 0; i < 2; ++i)
            #pragma unroll
            for (int j = 0; j < 4; ++j)
                acc[i][j] = __builtin_amdgcn_mfma_f32_16x16x32_f16(af[i], bf[j], acc[i][j], 0, 0, 0);
        __syncthreads();
    }
    // xl tile -> padded LDS (bias + relu)
    #pragma unroll
    for (int i = 0; i < 2; ++i)
        #pragma unroll
        for (int j = 0; j < 4; ++j) {
            int col = wc * 64 + j * 16 + fr;
            float bc = gb2[col];
            #pragma unroll
            for (int r = 0; r < 4; ++r) {
                int row = wr * 32 + i * 16 + rq * 4 + r;
                xlt[row][col] = (_Float16)fmaxf(acc[i][j][r] + bc, 0.f);
            }
        }
    __syncthreads();

    // ---- phase 2: classifier GEMM (K=256) + fused dot ----
    const float a0 = attn[0], a1 = attn[1];
    f32x4 acc2[8] = {};
    for (int it = 0; it < 8; ++it) {
        int k0 = it * 32, kg = k0 + kseg;
        uint4 av;
        if (kg < 128) {
            uint4 u = *(const uint4*)&xlt[srow][kg];
            float s0 = 0.f, s1 = 0.f, s2 = 0.f, s3 = 0.f, s4 = 0.f, s5 = 0.f, s6 = 0.f, s7 = 0.f;
            for (int q = rs; q < re; ++q) {
                uint4 o = *(const uint4*)(oe2 + (size_t)rowList[q] * 128 + kg);
                s0 += bflo(o.x); s1 += bfhi(o.x); s2 += bflo(o.y); s3 += bfhi(o.y);
                s4 += bflo(o.z); s5 += bfhi(o.z); s6 += bflo(o.w); s7 += bfhi(o.w);
            }
            float4 c0 = *(const float4*)(c2b + kg);
            float4 c1 = *(const float4*)(c2b + kg + 4);
            float2 g0 = h2f2(u.x), g1 = h2f2(u.y), g2 = h2f2(u.z), g3 = h2f2(u.w);
            av.x = pkh(a0 * g0.x + a1 * sigmoidf_(dv * s0 + c0.x),
                       a0 * g0.y + a1 * sigmoidf_(dv * s1 + c0.y));
            av.y = pkh(a0 * g1.x + a1 * sigmoidf_(dv * s2 + c0.z),
                       a0 * g1.y + a1 * sigmoidf_(dv * s3 + c0.w));
            av.z = pkh(a0 * g2.x + a1 * sigmoidf_(dv * s4 + c1.x),
                       a0 * g2.y + a1 * sigmoidf_(dv * s5 + c1.y));
            av.w = pkh(a0 * g3.x + a1 * sigmoidf_(dv * s6 + c1.z),
                       a0 * g3.y + a1 * sigmoidf_(dv * s7 + c1.w));
        } else {
            av = *(const uint4*)(geh + (size_t)gi * 128 + kg - 128);
        }
        *(uint4*)&As[srow][kseg] = av;
        *(uint4*)&Bs[nr][kb]     = *(const uint4*)(clw1t + (size_t)nr * 256 + k0 + kb);
        *(uint4*)&Bs[nr][kb + 8] = *(const uint4*)(clw1t + (size_t)nr * 256 + k0 + kb + 8);
        __syncthreads();
        f16x8 af = *(const f16x8*)&As[wave * 16 + fr][krow];
        #pragma unroll
        for (int j = 0; j < 8; ++j) {
            f16x8 bf = *(const f16x8*)&Bs[j * 16 + fr][krow];
            acc2[j] = __builtin_amdgcn_mfma_f32_16x16x32_f16(af, bf, acc2[j], 0, 0, 0);
        }
        __syncthreads();
    }
    // epilogue: relu(+clb1), dot w2, 16-lane reduce, sigmoid, scatter via perm
    float rsum[4] = {0.f, 0.f, 0.f, 0.f};
    #pragma unroll
    for (int j = 0; j < 8; ++j) {
        int colg = j * 16 + fr;
        float bc = clb1[colg];
        float wv = w2[colg];
        #pragma unroll
        for (int r = 0; r < 4; ++r)
            rsum[r] += fmaxf(acc2[j][r] + bc, 0.f) * wv;
    }
    #pragma unroll
    for (int m = 1; m < 16; m <<= 1) {
        #pragma unroll
        for (int r = 0; r < 4; ++r) rsum[r] += __shfl_xor(rsum[r], m, 64);
    }
    if (fr == 0) {
        float bb = b2[0];
        #pragma unroll
        for (int r = 0; r < 4; ++r)
            out[perm[m0 + wave * 16 + rq * 4 + r]] = sigmoidf_(rsum[r] + bb);
    }
}

// =======================================================================================
extern "C" void kernel_launch(void* const* d_in, const int* in_sizes, int n_in,
                              void* d_out, int out_size, void* d_ws, size_t ws_size,
                              hipStream_t stream)
{
    const float* x     = (const float*)d_in[0];
    const float* ge    = (const float*)d_in[1];
    const int*   ei    = (const int*)d_in[2];
    const int*   batch = (const int*)d_in[4];
    const int*   he    = (const int*)d_in[5];
    const float* hw_w1 = (const float*)d_in[6];
    const float* hw_b1 = (const float*)d_in[7];
    const float* hw_w2 = (const float*)d_in[8];
    const float* hw_b2 = (const float*)d_in[9];
    const float* c1_w  = (const float*)d_in[10];
    const float* c1_b  = (const float*)d_in[11];
    const float* c2_w  = (const float*)d_in[12];
    const float* c2_b  = (const float*)d_in[13];
    const float* g_w1  = (const float*)d_in[14];
    const float* g_b1  = (const float*)d_in[15];
    const float* g_w2  = (const float*)d_in[16];
    const float* g_b2  = (const float*)d_in[17];
    const float* cl_w1 = (const float*)d_in[18];
    const float* cl_b1 = (const float*)d_in[19];
    const float* cl_w2 = (const float*)d_in[20];
    const float* cl_b2 = (const float*)d_in[21];
    const float* attn  = (const float*)d_in[22];
    float* out = (float*)d_out;

    char* ws = (char*)d_ws;
    size_t off = 0;
    auto alloc = [&](size_t nb) -> void* {
        off = (off + 255) & ~(size_t)255;
        void* p = ws + off;
        off += nb;
        return p;
    };
    // ---- zero region (one memset): D, Bcnt, rowCnt, colCur, rowCur, ecnt, ecur ----
    float* D      = (float*)alloc((size_t)EDGES * 4);   // becomes Dinv in place
    int*   Bcnt   = (int*)  alloc((size_t)NODES * 4);
    int*   rowCnt = (int*)  alloc((size_t)EDGES * 4);
    int*   colCur = (int*)  alloc((size_t)NODES * 4);
    int*   rowCur = (int*)  alloc((size_t)EDGES * 4);
    int*   ecnt   = (int*)  alloc((size_t)NODES * 4);
    int*   ecur   = (int*)  alloc((size_t)NODES * 4);
    size_t zero_end = off;
    // ---- other small arrays ----
    float* node_w = (float*)alloc((size_t)NODES * 4);
    float* Binv   = (float*)alloc((size_t)NODES * 4);
    int*   colOff = (int*)  alloc((size_t)(NODES + 1) * 4);
    int*   rowOff = (int*)  alloc((size_t)(EDGES + 1) * 4);
    int*   eoff   = (int*)  alloc((size_t)(NODES + 1) * 4);
    int*   colList= (int*)  alloc((size_t)NNZ_ * 4);
    int*   rowList= (int*)  alloc((size_t)NNZ_ * 4);
    int*   perm   = (int*)  alloc((size_t)EDGES * 4);
    int*   partA  = (int*)  alloc(1024 * 4);
    int*   partB  = (int*)  alloc(1024 * 4);
    int*   partC  = (int*)  alloc(1024 * 4);
    // dtype tables (~10 MB)
    __hip_bfloat16* xb    = (__hip_bfloat16*)alloc((size_t)NODES * FDIM * 2);
    _Float16* xh    = (_Float16*)alloc((size_t)NODES * FDIM * 2);
    _Float16* geh   = (_Float16*)alloc((size_t)512 * FDIM * 2);
    _Float16* gw1t  = (_Float16*)alloc((size_t)512 * 384 * 2);
    _Float16* gw2t  = (_Float16*)alloc((size_t)128 * 512 * 2);
    _Float16* clw1t = (_Float16*)alloc((size_t)128 * 256 * 2);
    // generator split tables (~33.5 MB)
    _Float16* xag   = (_Float16*)alloc((size_t)NODES * 512 * 2);
    _Float16* xb2   = (_Float16*)alloc((size_t)NODES * 512 * 2);
    _Float16* gc    = (_Float16*)alloc((size_t)512 * 512 * 2);
    // big buffers
    float* agg  = (float*)alloc((size_t)NODES * 256 * 4);                    // 16.4 MB
    __hip_bfloat16* oe1b = (__hip_bfloat16*)alloc((size_t)NODES * 256 * 2);  // 8.2 MB
    __hip_bfloat16* oe2  = (__hip_bfloat16*)alloc((size_t)NODES * 128 * 2);  // 4.1 MB
    __hip_bfloat16* er   = (__hip_bfloat16*)alloc((size_t)EDGES * 256 * 2);  // 131 MB

    hipMemsetAsync(D, 0, zero_end, stream);   // zeroes D..ecur (incl. align pads)

    hyperweight_k<<<NODES / 8, 128, 0, stream>>>(x, ge, batch, hw_w1, hw_b1, hw_w2, hw_b2, node_w);
    incidence_pass<<<NNZ_ / 256, 256, 0, stream>>>(he, node_w, D, Bcnt, rowCnt);
    inv_k<<<EDGES / 256, 256, 0, stream>>>(D, Bcnt, Binv, ei, ecnt);

    const int ncN = (NODES + 1023) / 1024;
    const int ncE = (EDGES + 1023) / 1024;
    reduce_chunks<<<ncN, 1024, 0, stream>>>(Bcnt, partA, NODES);
    scan_sums<<<1, 1024, 0, stream>>>(partA, ncN);
    scan_chunks<<<ncN, 1024, 0, stream>>>(Bcnt, partA, colOff, NODES);
    reduce_chunks<<<ncE, 1024, 0, stream>>>(rowCnt, partB, EDGES);
    scan_sums<<<1, 1024, 0, stream>>>(partB, ncE);
    scan_chunks<<<ncE, 1024, 0, stream>>>(rowCnt, partB, rowOff, EDGES);
    scatter_pass<<<NNZ_ / 256, 256, 0, stream>>>(he, colOff, rowOff, colCur, rowCur, colList, rowList);

    // edge sort-by-col (counting sort): eoff = scan(ecnt); perm
    reduce_chunks<<<ncN, 1024, 0, stream>>>(ecnt, partC, NODES);
    scan_sums<<<1, 1024, 0, stream>>>(partC, ncN);
    scan_chunks<<<ncN, 1024, 0, stream>>>(ecnt, partC, eoff, NODES);
    edge_scatter<<<EDGES / 256, 256, 0, stream>>>(ei, eoff, ecur, perm);

    // conversions / weight transposes (fp16 generator+classifier path)
    conv_x<<<(NODES * FDIM + 255) / 256, 256, 0, stream>>>(x, xb, xh, NODES * FDIM);
    conv_f16<<<(512 * FDIM + 255) / 256, 256, 0, stream>>>(ge, geh, 512 * FDIM);
    transpose_f16<<<(384 * 512 + 255) / 256, 256, 0, stream>>>(g_w1, gw1t, 384, 512);
    transpose_f16<<<(512 * 128 + 255) / 256, 256, 0, stream>>>(g_w2, gw2t, 512, 128);
    transpose_f16<<<(256 * 128 + 255) / 256, 256, 0, stream>>>(cl_w1, clw1t, 256, 128);

    // generator split tables: gc = ge@W[256:384]; xag = x@W[0:128] + gc[batch] + b1; xb2 = x@W[128:256]
    xw_f16<384, false><<<dim3(512 / 64, 4), 256, 0, stream>>>(geh, gw1t + 256, gc, nullptr, nullptr, nullptr);
    xw_f16<384, true><<<dim3(NODES / 64, 4), 256, 0, stream>>>(xh, gw1t, xag, gc, batch, g_b1);
    xw_f16<384, false><<<dim3(NODES / 64, 4), 256, 0, stream>>>(xh, gw1t + 128, xb2, nullptr, nullptr, nullptr);

    // conv1 (linear-commuted): oe1 = Binv ⊙ (agg1 @ c1_w)   [NODES,256] bf16
    col_gather_x<<<NODES, 128, 0, stream>>>(xb, ei, colOff, colList, agg);
    gemm_node<256, 256, true><<<dim3(NODES / 64, 4), 256, 0, stream>>>(agg, c1_w, Binv, oe1b);

    // conv2: er materialized, flat col-aggregation, oe2 = Binv ⊙ (agg2 @ c2_w)
    er_k<<<EDGES, 128, 0, stream>>>(oe1b, rowOff, rowList, D, c1_b, er);
    col_agg_er<<<NODES, 128, 0, stream>>>(er, colOff, colList, agg);
    gemm_node<256, 128, true><<<dim3(NODES / 64, 2), 256, 0, stream>>>(agg, c2_w, Binv, oe2);

    // fused generator-L2 + classifier (col-sorted edge order) -> out
    gencls_mfma<<<EDGES / 64, 256, 0, stream>>>(xag, xb2, gw2t, g_b2, geh, attn, clw1t, cl_b1,
                                                cl_w2, cl_b2, c2_b, oe2, ei, batch,
                                                rowOff, rowList, D, perm, out);
}